// Round 6
// baseline (1114.062 us; speedup 1.0000x reference)
//
#include <hip/hip_runtime.h>
#include <cstdint>
#include <cstddef>

// Problem constants (SuperGraphConstruction)
#define NN 100000      // nodes
#define NC 20000       // clusters
#define LATD 128
#define HIDD 512
#define EMBD 12
#define NES 160000     // super edges
#define NEB 800000     // bipartite edges

enum { ACT_NONE = 0, ACT_TANH = 1, ACT_RELU = 2 };

typedef __attribute__((ext_vector_type(8))) short bf16x8;
typedef __attribute__((ext_vector_type(4))) float f32x4;
typedef unsigned short ushort_t;

__device__ __forceinline__ float fast_tanh(float x) {
    return 1.f - 2.f / (__expf(2.f * x) + 1.f);
}
__device__ __forceinline__ ushort_t f2bf(float f) {
    union { float f; unsigned u; } x; x.f = f;
    unsigned r = x.u + 0x7FFFu + ((x.u >> 16) & 1u);  // RNE
    return (ushort_t)(r >> 16);
}
__device__ __forceinline__ float bf2f(ushort_t h) {
    union { unsigned u; float f; } x; x.u = ((unsigned)h) << 16;
    return x.f;
}

typedef __attribute__((address_space(1))) void gvoid_t;
typedef __attribute__((address_space(3))) void svoid_t;
__device__ __forceinline__ void gload_lds16(const void* g, void* l) {
    // async global->LDS, 16B/lane; LDS dest = wave-uniform base + lane*16
    __builtin_amdgcn_global_load_lds((gvoid_t*)g, (svoid_t*)l, 16, 0, 0);
}

// ---------------------------------------------------------------------------
// fp32 -> bf16 elementwise (n multiple of 8 assumed at call sites)
// ---------------------------------------------------------------------------
__global__ __launch_bounds__(256) void conv_f2b_kernel(
    const float* __restrict__ in, ushort_t* __restrict__ out, long n)
{
    long i = ((long)blockIdx.x * 256 + threadIdx.x) * 8;
    long stride = (long)gridDim.x * 256 * 8;
    for (; i + 7 < n; i += stride) {
        float4 a = *(const float4*)(in + i);
        float4 b = *(const float4*)(in + i + 4);
        ushort_t o[8] = { f2bf(a.x), f2bf(a.y), f2bf(a.z), f2bf(a.w),
                          f2bf(b.x), f2bf(b.y), f2bf(b.z), f2bf(b.w) };
        *(int4*)(out + i) = *(int4*)o;
    }
}

// W [K][N] fp32 -> Wt [N][K] bf16  (small, launched per weight)
__global__ __launch_bounds__(256) void transpose_conv_kernel(
    const float* __restrict__ W, ushort_t* __restrict__ Wt, int K, int N)
{
    int i = blockIdx.x * 256 + threadIdx.x;
    if (i >= K * N) return;
    int n = i / K, k = i % K;
    Wt[i] = f2bf(W[(size_t)k * N + n]);
}

// ---------------------------------------------------------------------------
// bf16 MFMA GEMM (m97 structure): C[M,N] = act(A[M,K] @ B[K,N] + bias)
//   A bf16 row-major [M][K]; Bt bf16 PRE-TRANSPOSED [N][K]; bias fp32.
//   GATHER: A row m = concat(gsrc[g0[m]][0:128], gsrc[g1[m]][0:128]), K=256.
//   BM=BN=128, BK=64; 256 threads = 4 waves (2x2); each wave 64x64 out.
//   Staging via global_load_lds(16B), LINEAR LDS [128][64] (no pad).
//   N multiple of 128, K multiple of 64. M-tail: source row clamped.
// ---------------------------------------------------------------------------
template<int ACT, bool GATHER, bool OUT_BF16>
__global__ __launch_bounds__(256) void gemm_mfma(
    const ushort_t* __restrict__ A, const ushort_t* __restrict__ Bt,
    const float* __restrict__ bias, void* __restrict__ Cv,
    int M, int N, int K,
    const int* __restrict__ g0, const int* __restrict__ g1,
    const ushort_t* __restrict__ gsrc)
{
    __shared__ ushort_t As[128 * 64];   // linear: row*64 + col
    __shared__ ushort_t Bs[128 * 64];

    const int tid = threadIdx.x;
    const int m0 = blockIdx.y * 128, n0 = blockIdx.x * 128;
    const int w = tid >> 6, lane = tid & 63;
    const int wm = w >> 1, wn = w & 1;
    const int lr = lane & 15, lg = lane >> 4;
    const int lrow = lane >> 3;        // 0..7 row within 8-row chunk
    const int lcol = (lane & 7) * 8;   // bf16 col within 64-col row

    f32x4 acc[4][4];
#pragma unroll
    for (int i = 0; i < 4; ++i)
#pragma unroll
        for (int j = 0; j < 4; ++j) acc[i][j] = (f32x4){0.f, 0.f, 0.f, 0.f};

    for (int k0 = 0; k0 < K; k0 += 64) {
        // ---- stage tiles: each wave issues 4 A-chunks + 4 B-chunks (1KB each)
#pragma unroll
        for (int i = 0; i < 4; ++i) {
            int c = w * 4 + i;            // chunk 0..15 (8 rows each)
            int row = c * 8 + lrow;       // tile row 0..127
            int gm = m0 + row; if (gm >= M) gm = M - 1;  // clamp tail
            const ushort_t* ga;
            if (!GATHER) {
                ga = A + (size_t)gm * K + k0 + lcol;
            } else {
                int src = (k0 >= LATD) ? g1[gm] : g0[gm];
                ga = gsrc + (size_t)src * LATD + (k0 & (LATD - 1)) + lcol;
            }
            gload_lds16(ga, As + c * 512);
            const ushort_t* gb = Bt + (size_t)(n0 + row) * K + k0 + lcol;
            gload_lds16(gb, Bs + c * 512);
        }
        __syncthreads();

        // ---- 2 k-steps of 32 ----
#pragma unroll
        for (int ks = 0; ks < 2; ++ks) {
            bf16x8 af[4], bf[4];
#pragma unroll
            for (int mt = 0; mt < 4; ++mt)
                af[mt] = *(const bf16x8*)&As[(wm * 64 + mt * 16 + lr) * 64 + ks * 32 + lg * 8];
#pragma unroll
            for (int nt = 0; nt < 4; ++nt)
                bf[nt] = *(const bf16x8*)&Bs[(wn * 64 + nt * 16 + lr) * 64 + ks * 32 + lg * 8];
#pragma unroll
            for (int mt = 0; mt < 4; ++mt)
#pragma unroll
                for (int nt = 0; nt < 4; ++nt)
                    acc[mt][nt] = __builtin_amdgcn_mfma_f32_16x16x32_bf16(
                        af[mt], bf[nt], acc[mt][nt], 0, 0, 0);
        }
        __syncthreads();
    }

    // ---- epilogue: D lane,reg -> row=(lane>>4)*4+reg, col=lane&15 ----
#pragma unroll
    for (int nt = 0; nt < 4; ++nt) {
        int col = n0 + wn * 64 + nt * 16 + lr;
        float bv = bias[col];
#pragma unroll
        for (int mt = 0; mt < 4; ++mt) {
#pragma unroll
            for (int r = 0; r < 4; ++r) {
                int row = m0 + wm * 64 + mt * 16 + lg * 4 + r;
                if (row >= M) continue;
                float v = acc[mt][nt][r] + bv;
                if (ACT == ACT_TANH) v = fast_tanh(v);
                else if (ACT == ACT_RELU) v = fmaxf(v, 0.f);
                if (OUT_BF16) ((ushort_t*)Cv)[(size_t)row * N + col] = f2bf(v);
                else ((float*)Cv)[(size_t)row * N + col] = v;
            }
        }
    }
}

// ---------------------------------------------------------------------------
// embeddings = l2norm(h2 @ Wc3 + bc3); THREAD-per-row; h2 bf16.
// ---------------------------------------------------------------------------
__global__ __launch_bounds__(256) void emb_kernel(
    const ushort_t* __restrict__ h2, const float* __restrict__ W,  // [512][12]
    const float* __restrict__ bias, float* __restrict__ out, int M)
{
    __shared__ float Wl[HIDD * EMBD];  // same layout as W (row-major [k][j])
    for (int i = threadIdx.x; i < HIDD * EMBD; i += 256) Wl[i] = W[i];
    __syncthreads();

    int m = blockIdx.x * 256 + threadIdx.x;
    if (m >= M) return;
    const ushort_t* row = h2 + (size_t)m * HIDD;

    float acc[EMBD] = {};
#pragma unroll 2
    for (int k0 = 0; k0 < HIDD; k0 += 8) {
        bf16x8 v = *(const bf16x8*)(row + k0);
        float f[8];
#pragma unroll
        for (int u = 0; u < 8; ++u) f[u] = bf2f((ushort_t)v[u]);
#pragma unroll
        for (int u = 0; u < 8; ++u) {
            const float* wr = &Wl[(k0 + u) * EMBD];
#pragma unroll
            for (int j = 0; j < EMBD; ++j) acc[j] += f[u] * wr[j];
        }
    }
    float vv[EMBD];
    float ss = 0.f;
#pragma unroll
    for (int j = 0; j < EMBD; ++j) { vv[j] = acc[j] + bias[j]; ss += vv[j] * vv[j]; }
    float inv = 1.f / fmaxf(sqrtf(ss), 1e-12f);
#pragma unroll
    for (int j = 0; j < EMBD; ++j) out[(size_t)m * EMBD + j] = vv[j] * inv;
}

// ---------------------------------------------------------------------------
// cluster sums + counts: thread-per-node, float4 row loads
// ---------------------------------------------------------------------------
__global__ void cluster_accum(const float* __restrict__ emb,
                              const int* __restrict__ clusters,
                              float* __restrict__ csums, float* __restrict__ ccnt)
{
    int n = blockIdx.x * 256 + threadIdx.x;
    if (n >= NN) return;
    int c = clusters[n];
    const float4* row = (const float4*)(emb + (size_t)n * EMBD);
    float4 r0 = row[0], r1 = row[1], r2 = row[2];
    float* dst = &csums[(size_t)c * EMBD];
    atomicAdd(&dst[0], r0.x);  atomicAdd(&dst[1], r0.y);
    atomicAdd(&dst[2], r0.z);  atomicAdd(&dst[3], r0.w);
    atomicAdd(&dst[4], r1.x);  atomicAdd(&dst[5], r1.y);
    atomicAdd(&dst[6], r1.z);  atomicAdd(&dst[7], r1.w);
    atomicAdd(&dst[8], r2.x);  atomicAdd(&dst[9], r2.y);
    atomicAdd(&dst[10], r2.z); atomicAdd(&dst[11], r2.w);
    atomicAdd(&ccnt[c], 1.f);
}

__global__ void means_kernel(const float* __restrict__ csums,
                             const float* __restrict__ ccnt,
                             float* __restrict__ means)
{
    int c = blockIdx.x * 256 + threadIdx.x;
    if (c >= NC) return;
    float cv = fmaxf(ccnt[c], 1.f);
    float v[EMBD];
    float ss = 0.f;
#pragma unroll
    for (int j = 0; j < EMBD; ++j) {
        v[j] = csums[(size_t)c * EMBD + j] / cv;
        ss += v[j] * v[j];
    }
    float inv = 1.f / fmaxf(sqrtf(ss), 1e-12f);
#pragma unroll
    for (int j = 0; j < EMBD; ++j) means[(size_t)c * EMBD + j] = v[j] * inv;
}

// ---------------------------------------------------------------------------
// block-reduced sum/sumsq (pre-accumulated per-thread) -> atomics
// ---------------------------------------------------------------------------
__device__ __forceinline__ void block_stats2(float x, float x2, float* s_sum, float* s_sumsq)
{
#pragma unroll
    for (int s = 32; s >= 1; s >>= 1) {
        x += __shfl_xor(x, s, 64);
        x2 += __shfl_xor(x2, s, 64);
    }
    __shared__ float w0[4], w1[4];
    int lane = threadIdx.x & 63, w = threadIdx.x >> 6;
    if (lane == 0) { w0[w] = x; w1[w] = x2; }
    __syncthreads();
    if (threadIdx.x == 0) {
        float a = 0.f, b = 0.f;
        for (int i = 0; i < 4; ++i) { a += w0[i]; b += w1[i]; }
        atomicAdd(s_sum, a);
        atomicAdd(s_sumsq, b);
    }
}

// ---------------------------------------------------------------------------
// sg_lik, 4 edges/thread (NES % 4 == 0)
// ---------------------------------------------------------------------------
__global__ __launch_bounds__(256) void sg_lik_kernel(
    const float* __restrict__ means, const int* __restrict__ sg0,
    const int* __restrict__ sg1, float* __restrict__ sg_lik, float* __restrict__ stats)
{
    int base = (blockIdx.x * 256 + threadIdx.x) * 4;
    float xs = 0.f, xs2 = 0.f;
    if (base < NES) {
        int4 a4 = *(const int4*)(sg0 + base);
        int4 b4 = *(const int4*)(sg1 + base);
        int ai[4] = {a4.x, a4.y, a4.z, a4.w};
        int bi[4] = {b4.x, b4.y, b4.z, b4.w};
        float4 av[4][3], bv[4][3];
#pragma unroll
        for (int i = 0; i < 4; ++i) {
            const float4* ap = (const float4*)(means + (size_t)ai[i] * EMBD);
            const float4* bp = (const float4*)(means + (size_t)bi[i] * EMBD);
            av[i][0] = ap[0]; av[i][1] = ap[1]; av[i][2] = ap[2];
            bv[i][0] = bp[0]; bv[i][1] = bp[1]; bv[i][2] = bp[2];
        }
        float4 o;
        float* op = (float*)&o;
#pragma unroll
        for (int i = 0; i < 4; ++i) {
            float s = av[i][0].x * bv[i][0].x + av[i][0].y * bv[i][0].y
                    + av[i][0].z * bv[i][0].z + av[i][0].w * bv[i][0].w
                    + av[i][1].x * bv[i][1].x + av[i][1].y * bv[i][1].y
                    + av[i][1].z * bv[i][1].z + av[i][1].w * bv[i][1].w
                    + av[i][2].x * bv[i][2].x + av[i][2].y * bv[i][2].y
                    + av[i][2].z * bv[i][2].z + av[i][2].w * bv[i][2].w;
            op[i] = s;
            xs += s; xs2 += s * s;
        }
        *(float4*)(sg_lik + base) = o;
    }
    block_stats2(xs, xs2, &stats[0], &stats[1]);
}

__global__ __launch_bounds__(256) void sgw_kernel(
    const float* __restrict__ sg_lik, const float* __restrict__ stats,
    const float* __restrict__ gamma, const float* __restrict__ beta,
    float* __restrict__ out)
{
    int base = (blockIdx.x * 256 + threadIdx.x) * 4;
    if (base >= NES) return;
    float m = stats[0] / (float)NES;
    float var = stats[1] / (float)NES - m * m;
    float rs = rsqrtf(var + 1e-5f) * gamma[0];
    float4 v = *(const float4*)(sg_lik + base);
    float4 o;
    o.x = 1.f / (1.f + __expf(-((v.x - m) * rs + beta[0])));
    o.y = 1.f / (1.f + __expf(-((v.y - m) * rs + beta[0])));
    o.z = 1.f / (1.f + __expf(-((v.z - m) * rs + beta[0])));
    o.w = 1.f / (1.f + __expf(-((v.w - m) * rs + beta[0])));
    *(float4*)(out + base) = o;
}

// ---------------------------------------------------------------------------
// bg_lik + histogram, 4 edges/thread (NEB % 4 == 0)
// ---------------------------------------------------------------------------
__global__ __launch_bounds__(256) void bg_lik_kernel(
    const float* __restrict__ emb, const float* __restrict__ means,
    const int* __restrict__ bg_src, const int* __restrict__ bg_dst,
    float* __restrict__ bg_lik, float* __restrict__ stats, int* __restrict__ cnt)
{
    int base = (blockIdx.x * 256 + threadIdx.x) * 4;
    float xs = 0.f, xs2 = 0.f;
    if (base < NEB) {
        int4 s4 = *(const int4*)(bg_src + base);
        int4 d4 = *(const int4*)(bg_dst + base);
        int si[4] = {s4.x, s4.y, s4.z, s4.w};
        int di[4] = {d4.x, d4.y, d4.z, d4.w};
        float4 av[4][3], bv[4][3];
#pragma unroll
        for (int i = 0; i < 4; ++i) {
            const float4* ap = (const float4*)(emb + (size_t)si[i] * EMBD);
            const float4* bp = (const float4*)(means + (size_t)di[i] * EMBD);
            av[i][0] = ap[0]; av[i][1] = ap[1]; av[i][2] = ap[2];
            bv[i][0] = bp[0]; bv[i][1] = bp[1]; bv[i][2] = bp[2];
        }
#pragma unroll
        for (int i = 0; i < 4; ++i) atomicAdd(&cnt[di[i]], 1);
        float4 o;
        float* op = (float*)&o;
#pragma unroll
        for (int i = 0; i < 4; ++i) {
            float s = av[i][0].x * bv[i][0].x + av[i][0].y * bv[i][0].y
                    + av[i][0].z * bv[i][0].z + av[i][0].w * bv[i][0].w
                    + av[i][1].x * bv[i][1].x + av[i][1].y * bv[i][1].y
                    + av[i][1].z * bv[i][1].z + av[i][1].w * bv[i][1].w
                    + av[i][2].x * bv[i][2].x + av[i][2].y * bv[i][2].y
                    + av[i][2].z * bv[i][2].z + av[i][2].w * bv[i][2].w;
            op[i] = s;
            xs += s; xs2 += s * s;
        }
        *(float4*)(bg_lik + base) = o;
    }
    block_stats2(xs, xs2, &stats[2], &stats[3]);
}

__global__ __launch_bounds__(256) void bw_kernel(
    const float* __restrict__ bg_lik, const float* __restrict__ stats,
    const float* __restrict__ gamma, const float* __restrict__ beta,
    const int* __restrict__ bg_src, float* __restrict__ bw, float* __restrict__ denom)
{
    int base = (blockIdx.x * 256 + threadIdx.x) * 4;
    if (base >= NEB) return;
    float m = stats[2] / (float)NEB;
    float var = stats[3] / (float)NEB - m * m;
    float rs = rsqrtf(var + 1e-5f) * gamma[0];
    int4 s4 = *(const int4*)(bg_src + base);
    int si[4] = {s4.x, s4.y, s4.z, s4.w};
    float4 v = *(const float4*)(bg_lik + base);
    float vi[4] = {v.x, v.y, v.z, v.w};
    float4 o;
    float* op = (float*)&o;
#pragma unroll
    for (int i = 0; i < 4; ++i) {
        float w = __expf((vi[i] - m) * rs + beta[0]);
        op[i] = w;
        atomicAdd(&denom[si[i]], w);
    }
    *(float4*)(bw + base) = o;
}

__global__ __launch_bounds__(256) void bw_norm_kernel(
    float* __restrict__ bw, const float* __restrict__ denom,
    const int* __restrict__ bg_src, float* __restrict__ out)
{
    int base = (blockIdx.x * 256 + threadIdx.x) * 4;
    if (base >= NEB) return;
    int4 s4 = *(const int4*)(bg_src + base);
    int si[4] = {s4.x, s4.y, s4.z, s4.w};
    float dv[4];
#pragma unroll
    for (int i = 0; i < 4; ++i) dv[i] = denom[si[i]];
    float4 v = *(const float4*)(bw + base);
    float4 o;
    o.x = v.x / (1e-12f + dv[0]);
    o.y = v.y / (1e-12f + dv[1]);
    o.z = v.z / (1e-12f + dv[2]);
    o.w = v.w / (1e-12f + dv[3]);
    *(float4*)(bw + base) = o;
    *(float4*)(out + base) = o;
}

// ---------------------------------------------------------------------------
__global__ __launch_bounds__(1024) void scan_kernel(
    const int* __restrict__ cnt, int* __restrict__ offs, int C)
{
    __shared__ int wsum[16];
    __shared__ int carry_s, ctot_s;
    const int tid = threadIdx.x;
    const int lane = tid & 63, w = tid >> 6;
    if (tid == 0) carry_s = 0;
    __syncthreads();
    for (int base = 0; base < C; base += 1024) {
        int i = base + tid;
        int v = (i < C) ? cnt[i] : 0;
        int x = v;
#pragma unroll
        for (int s = 1; s < 64; s <<= 1) {
            int y = __shfl_up(x, s, 64);
            if (lane >= s) x += y;
        }
        if (lane == 63) wsum[w] = x;
        __syncthreads();
        if (tid == 0) {
            int s = 0;
            for (int k = 0; k < 16; ++k) { int t = wsum[k]; wsum[k] = s; s += t; }
            ctot_s = s;
        }
        __syncthreads();
        int excl = carry_s + wsum[w] + (x - v);
        if (i < C) offs[i] = excl;
        __syncthreads();
        if (tid == 0) carry_s += ctot_s;
        __syncthreads();
    }
    if (tid == 0) offs[C] = carry_s;
}

__global__ void scatter_kernel(const int* __restrict__ bg_dst,
                               const int* __restrict__ offs,
                               int* __restrict__ fill, int* __restrict__ eids)
{
    int base = (blockIdx.x * 256 + threadIdx.x) * 4;
    if (base >= NEB) return;
    int4 d4 = *(const int4*)(bg_dst + base);
    int di[4] = {d4.x, d4.y, d4.z, d4.w};
#pragma unroll
    for (int i = 0; i < 4; ++i) {
        int p = atomicAdd(&fill[di[i]], 1);
        eids[offs[di[i]] + p] = base + i;
    }
}

// ---------------------------------------------------------------------------
// supernodes[c][:] = sum_{e: bg_dst[e]==c} bw[e]*nmsg[bg_src[e]][:]  (nmsg bf16)
// x4 unrolled: 4 independent row-gathers in flight per block.
// ---------------------------------------------------------------------------
__global__ __launch_bounds__(128) void supernodes_kernel(
    const ushort_t* __restrict__ nmsg, const float* __restrict__ bw,
    const int* __restrict__ bg_src, const int* __restrict__ eids,
    const int* __restrict__ offs, float* __restrict__ sn)
{
    int c = blockIdx.x;
    int t = threadIdx.x;
    int beg = offs[c], end = offs[c + 1];
    float a0 = 0.f, a1 = 0.f, a2 = 0.f, a3 = 0.f;
    int p = beg;
    for (; p + 3 < end; p += 4) {
        int e0 = eids[p], e1 = eids[p + 1], e2 = eids[p + 2], e3 = eids[p + 3];
        int s0 = bg_src[e0], s1 = bg_src[e1], s2 = bg_src[e2], s3 = bg_src[e3];
        float w0 = bw[e0], w1 = bw[e1], w2 = bw[e2], w3 = bw[e3];
        ushort_t v0 = nmsg[(size_t)s0 * LATD + t];
        ushort_t v1 = nmsg[(size_t)s1 * LATD + t];
        ushort_t v2 = nmsg[(size_t)s2 * LATD + t];
        ushort_t v3 = nmsg[(size_t)s3 * LATD + t];
        a0 += w0 * bf2f(v0);
        a1 += w1 * bf2f(v1);
        a2 += w2 * bf2f(v2);
        a3 += w3 * bf2f(v3);
    }
    for (; p < end; ++p) {
        int e = eids[p];
        a0 += bw[e] * bf2f(nmsg[(size_t)bg_src[e] * LATD + t]);
    }
    sn[(size_t)c * LATD + t] = a0 + a1 + a2 + a3;
}

// ---------------------------------------------------------------------------
extern "C" void kernel_launch(void* const* d_in, const int* in_sizes, int n_in,
                              void* d_out, int out_size, void* d_ws, size_t ws_size,
                              hipStream_t stream)
{
    const float* emb_nodes = (const float*)d_in[0];
    const float* enc_nodes = (const float*)d_in[1];
    const float* Wc1 = (const float*)d_in[2];  const float* bc1 = (const float*)d_in[3];
    const float* Wc2 = (const float*)d_in[4];  const float* bc2 = (const float*)d_in[5];
    const float* Wc3 = (const float*)d_in[6];  const float* bc3 = (const float*)d_in[7];
    const float* Wn1 = (const float*)d_in[8];  const float* cn1 = (const float*)d_in[9];
    const float* Wn2 = (const float*)d_in[10]; const float* cn2 = (const float*)d_in[11];
    const float* We1 = (const float*)d_in[12]; const float* ce1 = (const float*)d_in[13];
    const float* We2 = (const float*)d_in[14]; const float* ce2 = (const float*)d_in[15];
    const float* sg_gamma = (const float*)d_in[16]; const float* sg_beta = (const float*)d_in[17];
    const float* bg_gamma = (const float*)d_in[18]; const float* bg_beta = (const float*)d_in[19];
    const int* clusters = (const int*)d_in[20];
    const int* sg0 = (const int*)d_in[21];
    const int* sg1 = sg0 + NES;
    const int* bg_src = (const int*)d_in[22];
    const int* bg_dst = (const int*)d_in[23];

    // output layout (flat, return order)
    float* out_emb = (float*)d_out;                       // NN*EMBD
    float* out_sn  = out_emb + (size_t)NN * EMBD;         // NC*LATD
    float* out_se  = out_sn + (size_t)NC * LATD;          // NES*LATD
    float* out_bw  = out_se + (size_t)NES * LATD;         // NEB
    float* out_sew = out_bw + (size_t)NEB;                // NES

    // ---------------- workspace layout (byte cursor, 64B-aligned) ----------
    uintptr_t cur = (uintptr_t)d_ws;
    uintptr_t wend = cur + ws_size;
    auto alloc = [&](size_t bytes) -> void* {
        cur = (cur + 63) & ~(uintptr_t)63;
        void* p = (void*)cur;
        cur += bytes;
        return p;
    };

    // zeroed region (contiguous)
    float* zbase = (float*)alloc(((size_t)NC * EMBD + NC + NN + 8 + NC + NC) * 4);
    float* csums = zbase;
    float* ccnt  = csums + (size_t)NC * EMBD;
    float* denom = ccnt + NC;
    float* stats = denom + NN;
    int*   cnt   = (int*)(stats + 8);
    int*   fill  = cnt + NC;
    size_t zero_bytes = ((size_t)NC * EMBD + NC + NN + 8 + NC + NC) * 4;

    float* means  = (float*)alloc((size_t)NC * EMBD * 4);
    float* sg_lik = (float*)alloc((size_t)NES * 4);
    float* bg_lik = (float*)alloc((size_t)NEB * 4);
    float* bwv    = (float*)alloc((size_t)NEB * 4);
    int*   offs   = (int*)alloc((size_t)(NC + 1) * 4);
    int*   eids   = (int*)alloc((size_t)NEB * 4);

    ushort_t* xemb   = (ushort_t*)alloc((size_t)NN * LATD * 2);
    ushort_t* xenc   = (ushort_t*)alloc((size_t)NN * LATD * 2);
    ushort_t* nmsgb  = (ushort_t*)alloc((size_t)NN * LATD * 2);
    ushort_t* sn_bf  = (ushort_t*)alloc((size_t)NC * LATD * 2);
    ushort_t* Wc1t = (ushort_t*)alloc((size_t)LATD * HIDD * 2);
    ushort_t* Wc2t = (ushort_t*)alloc((size_t)HIDD * HIDD * 2);
    ushort_t* Wn1t = (ushort_t*)alloc((size_t)LATD * HIDD * 2);
    ushort_t* Wn2t = (ushort_t*)alloc((size_t)HIDD * LATD * 2);
    ushort_t* We1t = (ushort_t*)alloc((size_t)2 * LATD * HIDD * 2);
    ushort_t* We2t = (ushort_t*)alloc((size_t)HIDD * LATD * 2);

    cur = (cur + 63) & ~(uintptr_t)63;
    size_t rem_bytes = (wend > cur) ? (size_t)(wend - cur) : 0;
    size_t chunk_sz = (rem_bytes / (2 * (size_t)HIDD * 2)) & ~(size_t)127;
    if (chunk_sz > 51200) chunk_sz = 51200;
    if (chunk_sz < 256) return;  // fail soft
    const int CH = (int)chunk_sz;
    ushort_t* bufA = (ushort_t*)cur;
    ushort_t* bufB = bufA + (size_t)CH * HIDD;

    hipMemsetAsync(zbase, 0, zero_bytes, stream);

    dim3 blk(256);

    // ---- prep: input/weight conversions ----
    conv_f2b_kernel<<<2048, blk, 0, stream>>>(emb_nodes, xemb, (long)NN * LATD);
    conv_f2b_kernel<<<2048, blk, 0, stream>>>(enc_nodes, xenc, (long)NN * LATD);
    transpose_conv_kernel<<<(LATD * HIDD + 255) / 256, blk, 0, stream>>>(Wc1, Wc1t, LATD, HIDD);
    transpose_conv_kernel<<<(HIDD * HIDD + 255) / 256, blk, 0, stream>>>(Wc2, Wc2t, HIDD, HIDD);
    transpose_conv_kernel<<<(LATD * HIDD + 255) / 256, blk, 0, stream>>>(Wn1, Wn1t, LATD, HIDD);
    transpose_conv_kernel<<<(HIDD * LATD + 255) / 256, blk, 0, stream>>>(Wn2, Wn2t, HIDD, LATD);
    transpose_conv_kernel<<<(2 * LATD * HIDD + 255) / 256, blk, 0, stream>>>(We1, We1t, 2 * LATD, HIDD);
    transpose_conv_kernel<<<(HIDD * LATD + 255) / 256, blk, 0, stream>>>(We2, We2t, HIDD, LATD);

    // ---- fused node chain, chunked: xemb->h1->h2->embeddings ----
    for (int m0 = 0; m0 < NN; m0 += CH) {
        int cm = (NN - m0 < CH) ? (NN - m0) : CH;
        gemm_mfma<ACT_TANH, false, true><<<dim3(HIDD / 128, (cm + 127) / 128), blk, 0, stream>>>(
            xemb + (size_t)m0 * LATD, Wc1t, bc1, bufA, cm, HIDD, LATD, nullptr, nullptr, nullptr);
        gemm_mfma<ACT_TANH, false, true><<<dim3(HIDD / 128, (cm + 127) / 128), blk, 0, stream>>>(
            bufA, Wc2t, bc2, bufB, cm, HIDD, HIDD, nullptr, nullptr, nullptr);
        emb_kernel<<<(cm + 255) / 256, blk, 0, stream>>>(
            bufB, Wc3, bc3, out_emb + (size_t)m0 * EMBD, cm);
    }

    // ---- cluster means ----
    cluster_accum<<<(NN + 255) / 256, blk, 0, stream>>>(out_emb, clusters, csums, ccnt);
    means_kernel<<<(NC + 255) / 256, blk, 0, stream>>>(csums, ccnt, means);

    // ---- super edge weights (4 edges/thread) ----
    sg_lik_kernel<<<(NES / 4 + 255) / 256, blk, 0, stream>>>(means, sg0, sg1, sg_lik, stats);
    sgw_kernel<<<(NES / 4 + 255) / 256, blk, 0, stream>>>(sg_lik, stats, sg_gamma, sg_beta, out_sew);

    // ---- bipartite edge weights (hist fused; 4 edges/thread) ----
    bg_lik_kernel<<<(NEB / 4 + 255) / 256, blk, 0, stream>>>(out_emb, means, bg_src, bg_dst, bg_lik, stats, cnt);
    bw_kernel<<<(NEB / 4 + 255) / 256, blk, 0, stream>>>(bg_lik, stats, bg_gamma, bg_beta, bg_src, bwv, denom);
    bw_norm_kernel<<<(NEB / 4 + 255) / 256, blk, 0, stream>>>(bwv, denom, bg_src, out_bw);

    // ---- counting sort of edges by destination cluster ----
    scan_kernel<<<1, 1024, 0, stream>>>(cnt, offs, NC);
    scatter_kernel<<<(NEB / 4 + 255) / 256, blk, 0, stream>>>(bg_dst, offs, fill, eids);

    // ---- node messages, chunked: xenc->nm->nmsg(bf16, full) ----
    for (int m0 = 0; m0 < NN; m0 += CH) {
        int cm = (NN - m0 < CH) ? (NN - m0) : CH;
        gemm_mfma<ACT_RELU, false, true><<<dim3(HIDD / 128, (cm + 127) / 128), blk, 0, stream>>>(
            xenc + (size_t)m0 * LATD, Wn1t, cn1, bufA, cm, HIDD, LATD, nullptr, nullptr, nullptr);
        gemm_mfma<ACT_RELU, false, true><<<dim3(LATD / 128, (cm + 127) / 128), blk, 0, stream>>>(
            bufA, Wn2t, cn2, nmsgb + (size_t)m0 * LATD, cm, LATD, HIDD, nullptr, nullptr, nullptr);
    }

    // ---- supernodes (sorted edge lists, no atomics) ----
    supernodes_kernel<<<NC, 128, 0, stream>>>(nmsgb, bwv, bg_src, eids, offs, out_sn);
    conv_f2b_kernel<<<512, blk, 0, stream>>>(out_sn, sn_bf, (long)NC * LATD);

    // ---- superedges, chunked (bufA+bufB = one 2*CH-row region) ----
    const int CE = 2 * CH;
    for (int e0 = 0; e0 < NES; e0 += CE) {
        int ce = (NES - e0 < CE) ? (NES - e0) : CE;
        gemm_mfma<ACT_RELU, true, true><<<dim3(HIDD / 128, (ce + 127) / 128), blk, 0, stream>>>(
            nullptr, We1t, ce1, bufA, ce, HIDD, 2 * LATD, sg0 + e0, sg1 + e0, sn_bf);
        gemm_mfma<ACT_RELU, false, false><<<dim3(LATD / 128, (ce + 127) / 128), blk, 0, stream>>>(
            bufA, We2t, ce2, out_se + (size_t)e0 * LATD, ce, LATD, HIDD, nullptr, nullptr, nullptr);
    }
}

// Round 7
// 1023.013 us; speedup vs baseline: 1.0890x; 1.0890x over previous
//
#include <hip/hip_runtime.h>
#include <cstdint>
#include <cstddef>

// Problem constants (SuperGraphConstruction)
#define NN 100000      // nodes
#define NC 20000       // clusters
#define LATD 128
#define HIDD 512
#define EMBD 12
#define NES 160000     // super edges
#define NEB 800000     // bipartite edges

enum { ACT_NONE = 0, ACT_TANH = 1, ACT_RELU = 2 };

typedef __attribute__((ext_vector_type(8))) short bf16x8;
typedef __attribute__((ext_vector_type(4))) float f32x4;
typedef unsigned short ushort_t;

__device__ __forceinline__ float fast_tanh(float x) {
    return 1.f - 2.f / (__expf(2.f * x) + 1.f);
}
__device__ __forceinline__ ushort_t f2bf(float f) {
    union { float f; unsigned u; } x; x.f = f;
    unsigned r = x.u + 0x7FFFu + ((x.u >> 16) & 1u);  // RNE
    return (ushort_t)(r >> 16);
}
__device__ __forceinline__ float bf2f(ushort_t h) {
    union { unsigned u; float f; } x; x.u = ((unsigned)h) << 16;
    return x.f;
}

typedef __attribute__((address_space(1))) void gvoid_t;
typedef __attribute__((address_space(3))) void svoid_t;
__device__ __forceinline__ void gload_lds16(const void* g, void* l) {
    // async global->LDS, 16B/lane; LDS dest = wave-uniform base + lane*16
    __builtin_amdgcn_global_load_lds((gvoid_t*)g, (svoid_t*)l, 16, 0, 0);
}

// ---------------------------------------------------------------------------
// fp32 -> bf16 elementwise (n multiple of 8 assumed at call sites)
// ---------------------------------------------------------------------------
__global__ __launch_bounds__(256) void conv_f2b_kernel(
    const float* __restrict__ in, ushort_t* __restrict__ out, long n)
{
    long i = ((long)blockIdx.x * 256 + threadIdx.x) * 8;
    long stride = (long)gridDim.x * 256 * 8;
    for (; i + 7 < n; i += stride) {
        float4 a = *(const float4*)(in + i);
        float4 b = *(const float4*)(in + i + 4);
        ushort_t o[8] = { f2bf(a.x), f2bf(a.y), f2bf(a.z), f2bf(a.w),
                          f2bf(b.x), f2bf(b.y), f2bf(b.z), f2bf(b.w) };
        *(int4*)(out + i) = *(int4*)o;
    }
}

// W [K][N] fp32 -> Wt [N][K] bf16  (small, launched per weight)
__global__ __launch_bounds__(256) void transpose_conv_kernel(
    const float* __restrict__ W, ushort_t* __restrict__ Wt, int K, int N)
{
    int i = blockIdx.x * 256 + threadIdx.x;
    if (i >= K * N) return;
    int n = i / K, k = i % K;
    Wt[i] = f2bf(W[(size_t)k * N + n]);
}

// ---------------------------------------------------------------------------
// bf16 MFMA GEMM (m97 structure + T2 XOR swizzle): C = act(A @ B + bias)
//   A bf16 row-major [M][K]; Bt bf16 PRE-TRANSPOSED [N][K]; bias fp32.
//   GATHER: A row m = concat(gsrc[g0[m]][0:128], gsrc[g1[m]][0:128]), K=256.
//   BM=BN=128, BK=64; 256 threads = 4 waves (2x2); each wave 64x64 out.
//   LDS is LINEAR [128][64] (global_load_lds requires linear dest); the
//   bank-conflict fix (row stride 128B = full bank rotation -> 16-way) is
//   rule-#21 both-sides swizzle: physical 16B slot p of row r holds data
//   segment p^(r&7); staging pre-swizzles the GLOBAL source segment,
//   fragment reads XOR the slot with (row&7). Post-fix: 2-way max (free).
// ---------------------------------------------------------------------------
template<int ACT, bool GATHER, bool OUT_BF16>
__global__ __launch_bounds__(256) void gemm_mfma(
    const ushort_t* __restrict__ A, const ushort_t* __restrict__ Bt,
    const float* __restrict__ bias, void* __restrict__ Cv,
    int M, int N, int K,
    const int* __restrict__ g0, const int* __restrict__ g1,
    const ushort_t* __restrict__ gsrc)
{
    __shared__ ushort_t As[128 * 64];   // linear: row*64 + slot*8, swizzled data
    __shared__ ushort_t Bs[128 * 64];

    const int tid = threadIdx.x;
    const int m0 = blockIdx.y * 128, n0 = blockIdx.x * 128;
    const int w = tid >> 6, lane = tid & 63;
    const int wm = w >> 1, wn = w & 1;
    const int lr = lane & 15, lg = lane >> 4;
    const int lrow = lane >> 3;                    // 0..7 row within 8-row chunk
    const int seg  = (lane & 7) ^ lrow;            // inverse-swizzled source segment
    const int lcol = seg * 8;                      // bf16 col of that segment

    f32x4 acc[4][4];
#pragma unroll
    for (int i = 0; i < 4; ++i)
#pragma unroll
        for (int j = 0; j < 4; ++j) acc[i][j] = (f32x4){0.f, 0.f, 0.f, 0.f};

    for (int k0 = 0; k0 < K; k0 += 64) {
        // ---- stage tiles: each wave issues 4 A-chunks + 4 B-chunks (1KB each)
#pragma unroll
        for (int i = 0; i < 4; ++i) {
            int c = w * 4 + i;            // chunk 0..15 (8 rows each)
            int row = c * 8 + lrow;       // tile row 0..127  (row&7 == lrow)
            int gm = m0 + row; if (gm >= M) gm = M - 1;  // clamp tail
            const ushort_t* ga;
            if (!GATHER) {
                ga = A + (size_t)gm * K + k0 + lcol;
            } else {
                int src = (k0 >= LATD) ? g1[gm] : g0[gm];
                ga = gsrc + (size_t)src * LATD + (k0 & (LATD - 1)) + lcol;
            }
            gload_lds16(ga, As + c * 512);
            const ushort_t* gb = Bt + (size_t)(n0 + row) * K + k0 + lcol;
            gload_lds16(gb, Bs + c * 512);
        }
        __syncthreads();

        // ---- 2 k-steps of 32 (reads XOR slot with row&7) ----
#pragma unroll
        for (int ks = 0; ks < 2; ++ks) {
            bf16x8 af[4], bf[4];
#pragma unroll
            for (int mt = 0; mt < 4; ++mt) {
                int row = wm * 64 + mt * 16 + lr;
                int slot = (ks * 4 + lg) ^ (row & 7);
                af[mt] = *(const bf16x8*)&As[row * 64 + slot * 8];
            }
#pragma unroll
            for (int nt = 0; nt < 4; ++nt) {
                int row = wn * 64 + nt * 16 + lr;
                int slot = (ks * 4 + lg) ^ (row & 7);
                bf[nt] = *(const bf16x8*)&Bs[row * 64 + slot * 8];
            }
#pragma unroll
            for (int mt = 0; mt < 4; ++mt)
#pragma unroll
                for (int nt = 0; nt < 4; ++nt)
                    acc[mt][nt] = __builtin_amdgcn_mfma_f32_16x16x32_bf16(
                        af[mt], bf[nt], acc[mt][nt], 0, 0, 0);
        }
        __syncthreads();
    }

    // ---- epilogue: D lane,reg -> row=(lane>>4)*4+reg, col=lane&15 ----
#pragma unroll
    for (int nt = 0; nt < 4; ++nt) {
        int col = n0 + wn * 64 + nt * 16 + lr;
        float bv = bias[col];
#pragma unroll
        for (int mt = 0; mt < 4; ++mt) {
#pragma unroll
            for (int r = 0; r < 4; ++r) {
                int row = m0 + wm * 64 + mt * 16 + lg * 4 + r;
                if (row >= M) continue;
                float v = acc[mt][nt][r] + bv;
                if (ACT == ACT_TANH) v = fast_tanh(v);
                else if (ACT == ACT_RELU) v = fmaxf(v, 0.f);
                if (OUT_BF16) ((ushort_t*)Cv)[(size_t)row * N + col] = f2bf(v);
                else ((float*)Cv)[(size_t)row * N + col] = v;
            }
        }
    }
}

// ---------------------------------------------------------------------------
// embeddings = l2norm(h2 @ Wc3 + bc3); THREAD-per-row; h2 bf16.
// ---------------------------------------------------------------------------
__global__ __launch_bounds__(256) void emb_kernel(
    const ushort_t* __restrict__ h2, const float* __restrict__ W,  // [512][12]
    const float* __restrict__ bias, float* __restrict__ out, int M)
{
    __shared__ float Wl[HIDD * EMBD];  // same layout as W (row-major [k][j])
    for (int i = threadIdx.x; i < HIDD * EMBD; i += 256) Wl[i] = W[i];
    __syncthreads();

    int m = blockIdx.x * 256 + threadIdx.x;
    if (m >= M) return;
    const ushort_t* row = h2 + (size_t)m * HIDD;

    float acc[EMBD] = {};
#pragma unroll 2
    for (int k0 = 0; k0 < HIDD; k0 += 8) {
        bf16x8 v = *(const bf16x8*)(row + k0);
        float f[8];
#pragma unroll
        for (int u = 0; u < 8; ++u) f[u] = bf2f((ushort_t)v[u]);
#pragma unroll
        for (int u = 0; u < 8; ++u) {
            const float* wr = &Wl[(k0 + u) * EMBD];
#pragma unroll
            for (int j = 0; j < EMBD; ++j) acc[j] += f[u] * wr[j];
        }
    }
    float vv[EMBD];
    float ss = 0.f;
#pragma unroll
    for (int j = 0; j < EMBD; ++j) { vv[j] = acc[j] + bias[j]; ss += vv[j] * vv[j]; }
    float inv = 1.f / fmaxf(sqrtf(ss), 1e-12f);
#pragma unroll
    for (int j = 0; j < EMBD; ++j) out[(size_t)m * EMBD + j] = vv[j] * inv;
}

// ---------------------------------------------------------------------------
// cluster sums + counts: thread-per-node, float4 row loads
// ---------------------------------------------------------------------------
__global__ void cluster_accum(const float* __restrict__ emb,
                              const int* __restrict__ clusters,
                              float* __restrict__ csums, float* __restrict__ ccnt)
{
    int n = blockIdx.x * 256 + threadIdx.x;
    if (n >= NN) return;
    int c = clusters[n];
    const float4* row = (const float4*)(emb + (size_t)n * EMBD);
    float4 r0 = row[0], r1 = row[1], r2 = row[2];
    float* dst = &csums[(size_t)c * EMBD];
    atomicAdd(&dst[0], r0.x);  atomicAdd(&dst[1], r0.y);
    atomicAdd(&dst[2], r0.z);  atomicAdd(&dst[3], r0.w);
    atomicAdd(&dst[4], r1.x);  atomicAdd(&dst[5], r1.y);
    atomicAdd(&dst[6], r1.z);  atomicAdd(&dst[7], r1.w);
    atomicAdd(&dst[8], r2.x);  atomicAdd(&dst[9], r2.y);
    atomicAdd(&dst[10], r2.z); atomicAdd(&dst[11], r2.w);
    atomicAdd(&ccnt[c], 1.f);
}

__global__ void means_kernel(const float* __restrict__ csums,
                             const float* __restrict__ ccnt,
                             float* __restrict__ means)
{
    int c = blockIdx.x * 256 + threadIdx.x;
    if (c >= NC) return;
    float cv = fmaxf(ccnt[c], 1.f);
    float v[EMBD];
    float ss = 0.f;
#pragma unroll
    for (int j = 0; j < EMBD; ++j) {
        v[j] = csums[(size_t)c * EMBD + j] / cv;
        ss += v[j] * v[j];
    }
    float inv = 1.f / fmaxf(sqrtf(ss), 1e-12f);
#pragma unroll
    for (int j = 0; j < EMBD; ++j) means[(size_t)c * EMBD + j] = v[j] * inv;
}

// ---------------------------------------------------------------------------
// block-reduced sum/sumsq (pre-accumulated per-thread) -> atomics
// ---------------------------------------------------------------------------
__device__ __forceinline__ void block_stats2(float x, float x2, float* s_sum, float* s_sumsq)
{
#pragma unroll
    for (int s = 32; s >= 1; s >>= 1) {
        x += __shfl_xor(x, s, 64);
        x2 += __shfl_xor(x2, s, 64);
    }
    __shared__ float w0[4], w1[4];
    int lane = threadIdx.x & 63, w = threadIdx.x >> 6;
    if (lane == 0) { w0[w] = x; w1[w] = x2; }
    __syncthreads();
    if (threadIdx.x == 0) {
        float a = 0.f, b = 0.f;
        for (int i = 0; i < 4; ++i) { a += w0[i]; b += w1[i]; }
        atomicAdd(s_sum, a);
        atomicAdd(s_sumsq, b);
    }
}

// ---------------------------------------------------------------------------
// sg_lik, 4 edges/thread (NES % 4 == 0)
// ---------------------------------------------------------------------------
__global__ __launch_bounds__(256) void sg_lik_kernel(
    const float* __restrict__ means, const int* __restrict__ sg0,
    const int* __restrict__ sg1, float* __restrict__ sg_lik, float* __restrict__ stats)
{
    int base = (blockIdx.x * 256 + threadIdx.x) * 4;
    float xs = 0.f, xs2 = 0.f;
    if (base < NES) {
        int4 a4 = *(const int4*)(sg0 + base);
        int4 b4 = *(const int4*)(sg1 + base);
        int ai[4] = {a4.x, a4.y, a4.z, a4.w};
        int bi[4] = {b4.x, b4.y, b4.z, b4.w};
        float4 av[4][3], bv[4][3];
#pragma unroll
        for (int i = 0; i < 4; ++i) {
            const float4* ap = (const float4*)(means + (size_t)ai[i] * EMBD);
            const float4* bp = (const float4*)(means + (size_t)bi[i] * EMBD);
            av[i][0] = ap[0]; av[i][1] = ap[1]; av[i][2] = ap[2];
            bv[i][0] = bp[0]; bv[i][1] = bp[1]; bv[i][2] = bp[2];
        }
        float4 o;
        float* op = (float*)&o;
#pragma unroll
        for (int i = 0; i < 4; ++i) {
            float s = av[i][0].x * bv[i][0].x + av[i][0].y * bv[i][0].y
                    + av[i][0].z * bv[i][0].z + av[i][0].w * bv[i][0].w
                    + av[i][1].x * bv[i][1].x + av[i][1].y * bv[i][1].y
                    + av[i][1].z * bv[i][1].z + av[i][1].w * bv[i][1].w
                    + av[i][2].x * bv[i][2].x + av[i][2].y * bv[i][2].y
                    + av[i][2].z * bv[i][2].z + av[i][2].w * bv[i][2].w;
            op[i] = s;
            xs += s; xs2 += s * s;
        }
        *(float4*)(sg_lik + base) = o;
    }
    block_stats2(xs, xs2, &stats[0], &stats[1]);
}

__global__ __launch_bounds__(256) void sgw_kernel(
    const float* __restrict__ sg_lik, const float* __restrict__ stats,
    const float* __restrict__ gamma, const float* __restrict__ beta,
    float* __restrict__ out)
{
    int base = (blockIdx.x * 256 + threadIdx.x) * 4;
    if (base >= NES) return;
    float m = stats[0] / (float)NES;
    float var = stats[1] / (float)NES - m * m;
    float rs = rsqrtf(var + 1e-5f) * gamma[0];
    float4 v = *(const float4*)(sg_lik + base);
    float4 o;
    o.x = 1.f / (1.f + __expf(-((v.x - m) * rs + beta[0])));
    o.y = 1.f / (1.f + __expf(-((v.y - m) * rs + beta[0])));
    o.z = 1.f / (1.f + __expf(-((v.z - m) * rs + beta[0])));
    o.w = 1.f / (1.f + __expf(-((v.w - m) * rs + beta[0])));
    *(float4*)(out + base) = o;
}

// ---------------------------------------------------------------------------
// bg_lik + histogram, 4 edges/thread (NEB % 4 == 0)
// ---------------------------------------------------------------------------
__global__ __launch_bounds__(256) void bg_lik_kernel(
    const float* __restrict__ emb, const float* __restrict__ means,
    const int* __restrict__ bg_src, const int* __restrict__ bg_dst,
    float* __restrict__ bg_lik, float* __restrict__ stats, int* __restrict__ cnt)
{
    int base = (blockIdx.x * 256 + threadIdx.x) * 4;
    float xs = 0.f, xs2 = 0.f;
    if (base < NEB) {
        int4 s4 = *(const int4*)(bg_src + base);
        int4 d4 = *(const int4*)(bg_dst + base);
        int si[4] = {s4.x, s4.y, s4.z, s4.w};
        int di[4] = {d4.x, d4.y, d4.z, d4.w};
        float4 av[4][3], bv[4][3];
#pragma unroll
        for (int i = 0; i < 4; ++i) {
            const float4* ap = (const float4*)(emb + (size_t)si[i] * EMBD);
            const float4* bp = (const float4*)(means + (size_t)di[i] * EMBD);
            av[i][0] = ap[0]; av[i][1] = ap[1]; av[i][2] = ap[2];
            bv[i][0] = bp[0]; bv[i][1] = bp[1]; bv[i][2] = bp[2];
        }
#pragma unroll
        for (int i = 0; i < 4; ++i) atomicAdd(&cnt[di[i]], 1);
        float4 o;
        float* op = (float*)&o;
#pragma unroll
        for (int i = 0; i < 4; ++i) {
            float s = av[i][0].x * bv[i][0].x + av[i][0].y * bv[i][0].y
                    + av[i][0].z * bv[i][0].z + av[i][0].w * bv[i][0].w
                    + av[i][1].x * bv[i][1].x + av[i][1].y * bv[i][1].y
                    + av[i][1].z * bv[i][1].z + av[i][1].w * bv[i][1].w
                    + av[i][2].x * bv[i][2].x + av[i][2].y * bv[i][2].y
                    + av[i][2].z * bv[i][2].z + av[i][2].w * bv[i][2].w;
            op[i] = s;
            xs += s; xs2 += s * s;
        }
        *(float4*)(bg_lik + base) = o;
    }
    block_stats2(xs, xs2, &stats[2], &stats[3]);
}

__global__ __launch_bounds__(256) void bw_kernel(
    const float* __restrict__ bg_lik, const float* __restrict__ stats,
    const float* __restrict__ gamma, const float* __restrict__ beta,
    const int* __restrict__ bg_src, float* __restrict__ bw, float* __restrict__ denom)
{
    int base = (blockIdx.x * 256 + threadIdx.x) * 4;
    if (base >= NEB) return;
    float m = stats[2] / (float)NEB;
    float var = stats[3] / (float)NEB - m * m;
    float rs = rsqrtf(var + 1e-5f) * gamma[0];
    int4 s4 = *(const int4*)(bg_src + base);
    int si[4] = {s4.x, s4.y, s4.z, s4.w};
    float4 v = *(const float4*)(bg_lik + base);
    float vi[4] = {v.x, v.y, v.z, v.w};
    float4 o;
    float* op = (float*)&o;
#pragma unroll
    for (int i = 0; i < 4; ++i) {
        float w = __expf((vi[i] - m) * rs + beta[0]);
        op[i] = w;
        atomicAdd(&denom[si[i]], w);
    }
    *(float4*)(bw + base) = o;
}

__global__ __launch_bounds__(256) void bw_norm_kernel(
    float* __restrict__ bw, const float* __restrict__ denom,
    const int* __restrict__ bg_src, float* __restrict__ out)
{
    int base = (blockIdx.x * 256 + threadIdx.x) * 4;
    if (base >= NEB) return;
    int4 s4 = *(const int4*)(bg_src + base);
    int si[4] = {s4.x, s4.y, s4.z, s4.w};
    float dv[4];
#pragma unroll
    for (int i = 0; i < 4; ++i) dv[i] = denom[si[i]];
    float4 v = *(const float4*)(bw + base);
    float4 o;
    o.x = v.x / (1e-12f + dv[0]);
    o.y = v.y / (1e-12f + dv[1]);
    o.z = v.z / (1e-12f + dv[2]);
    o.w = v.w / (1e-12f + dv[3]);
    *(float4*)(bw + base) = o;
    *(float4*)(out + base) = o;
}

// ---------------------------------------------------------------------------
__global__ __launch_bounds__(1024) void scan_kernel(
    const int* __restrict__ cnt, int* __restrict__ offs, int C)
{
    __shared__ int wsum[16];
    __shared__ int carry_s, ctot_s;
    const int tid = threadIdx.x;
    const int lane = tid & 63, w = tid >> 6;
    if (tid == 0) carry_s = 0;
    __syncthreads();
    for (int base = 0; base < C; base += 1024) {
        int i = base + tid;
        int v = (i < C) ? cnt[i] : 0;
        int x = v;
#pragma unroll
        for (int s = 1; s < 64; s <<= 1) {
            int y = __shfl_up(x, s, 64);
            if (lane >= s) x += y;
        }
        if (lane == 63) wsum[w] = x;
        __syncthreads();
        if (tid == 0) {
            int s = 0;
            for (int k = 0; k < 16; ++k) { int t = wsum[k]; wsum[k] = s; s += t; }
            ctot_s = s;
        }
        __syncthreads();
        int excl = carry_s + wsum[w] + (x - v);
        if (i < C) offs[i] = excl;
        __syncthreads();
        if (tid == 0) carry_s += ctot_s;
        __syncthreads();
    }
    if (tid == 0) offs[C] = carry_s;
}

__global__ void scatter_kernel(const int* __restrict__ bg_dst,
                               const int* __restrict__ offs,
                               int* __restrict__ fill, int* __restrict__ eids)
{
    int base = (blockIdx.x * 256 + threadIdx.x) * 4;
    if (base >= NEB) return;
    int4 d4 = *(const int4*)(bg_dst + base);
    int di[4] = {d4.x, d4.y, d4.z, d4.w};
#pragma unroll
    for (int i = 0; i < 4; ++i) {
        int p = atomicAdd(&fill[di[i]], 1);
        eids[offs[di[i]] + p] = base + i;
    }
}

// ---------------------------------------------------------------------------
// supernodes[c][:] = sum_{e: bg_dst[e]==c} bw[e]*nmsg[bg_src[e]][:]  (nmsg bf16)
// x4 unrolled: 4 independent row-gathers in flight per block.
// ---------------------------------------------------------------------------
__global__ __launch_bounds__(128) void supernodes_kernel(
    const ushort_t* __restrict__ nmsg, const float* __restrict__ bw,
    const int* __restrict__ bg_src, const int* __restrict__ eids,
    const int* __restrict__ offs, float* __restrict__ sn)
{
    int c = blockIdx.x;
    int t = threadIdx.x;
    int beg = offs[c], end = offs[c + 1];
    float a0 = 0.f, a1 = 0.f, a2 = 0.f, a3 = 0.f;
    int p = beg;
    for (; p + 3 < end; p += 4) {
        int e0 = eids[p], e1 = eids[p + 1], e2 = eids[p + 2], e3 = eids[p + 3];
        int s0 = bg_src[e0], s1 = bg_src[e1], s2 = bg_src[e2], s3 = bg_src[e3];
        float w0 = bw[e0], w1 = bw[e1], w2 = bw[e2], w3 = bw[e3];
        ushort_t v0 = nmsg[(size_t)s0 * LATD + t];
        ushort_t v1 = nmsg[(size_t)s1 * LATD + t];
        ushort_t v2 = nmsg[(size_t)s2 * LATD + t];
        ushort_t v3 = nmsg[(size_t)s3 * LATD + t];
        a0 += w0 * bf2f(v0);
        a1 += w1 * bf2f(v1);
        a2 += w2 * bf2f(v2);
        a3 += w3 * bf2f(v3);
    }
    for (; p < end; ++p) {
        int e = eids[p];
        a0 += bw[e] * bf2f(nmsg[(size_t)bg_src[e] * LATD + t]);
    }
    sn[(size_t)c * LATD + t] = a0 + a1 + a2 + a3;
}

// ---------------------------------------------------------------------------
extern "C" void kernel_launch(void* const* d_in, const int* in_sizes, int n_in,
                              void* d_out, int out_size, void* d_ws, size_t ws_size,
                              hipStream_t stream)
{
    const float* emb_nodes = (const float*)d_in[0];
    const float* enc_nodes = (const float*)d_in[1];
    const float* Wc1 = (const float*)d_in[2];  const float* bc1 = (const float*)d_in[3];
    const float* Wc2 = (const float*)d_in[4];  const float* bc2 = (const float*)d_in[5];
    const float* Wc3 = (const float*)d_in[6];  const float* bc3 = (const float*)d_in[7];
    const float* Wn1 = (const float*)d_in[8];  const float* cn1 = (const float*)d_in[9];
    const float* Wn2 = (const float*)d_in[10]; const float* cn2 = (const float*)d_in[11];
    const float* We1 = (const float*)d_in[12]; const float* ce1 = (const float*)d_in[13];
    const float* We2 = (const float*)d_in[14]; const float* ce2 = (const float*)d_in[15];
    const float* sg_gamma = (const float*)d_in[16]; const float* sg_beta = (const float*)d_in[17];
    const float* bg_gamma = (const float*)d_in[18]; const float* bg_beta = (const float*)d_in[19];
    const int* clusters = (const int*)d_in[20];
    const int* sg0 = (const int*)d_in[21];
    const int* sg1 = sg0 + NES;
    const int* bg_src = (const int*)d_in[22];
    const int* bg_dst = (const int*)d_in[23];

    // output layout (flat, return order)
    float* out_emb = (float*)d_out;                       // NN*EMBD
    float* out_sn  = out_emb + (size_t)NN * EMBD;         // NC*LATD
    float* out_se  = out_sn + (size_t)NC * LATD;          // NES*LATD
    float* out_bw  = out_se + (size_t)NES * LATD;         // NEB
    float* out_sew = out_bw + (size_t)NEB;                // NES

    // ---------------- workspace layout (byte cursor, 64B-aligned) ----------
    uintptr_t cur = (uintptr_t)d_ws;
    uintptr_t wend = cur + ws_size;
    auto alloc = [&](size_t bytes) -> void* {
        cur = (cur + 63) & ~(uintptr_t)63;
        void* p = (void*)cur;
        cur += bytes;
        return p;
    };

    // zeroed region (contiguous)
    float* zbase = (float*)alloc(((size_t)NC * EMBD + NC + NN + 8 + NC + NC) * 4);
    float* csums = zbase;
    float* ccnt  = csums + (size_t)NC * EMBD;
    float* denom = ccnt + NC;
    float* stats = denom + NN;
    int*   cnt   = (int*)(stats + 8);
    int*   fill  = cnt + NC;
    size_t zero_bytes = ((size_t)NC * EMBD + NC + NN + 8 + NC + NC) * 4;

    float* means  = (float*)alloc((size_t)NC * EMBD * 4);
    float* sg_lik = (float*)alloc((size_t)NES * 4);
    float* bg_lik = (float*)alloc((size_t)NEB * 4);
    float* bwv    = (float*)alloc((size_t)NEB * 4);
    int*   offs   = (int*)alloc((size_t)(NC + 1) * 4);
    int*   eids   = (int*)alloc((size_t)NEB * 4);

    ushort_t* xemb   = (ushort_t*)alloc((size_t)NN * LATD * 2);
    ushort_t* xenc   = (ushort_t*)alloc((size_t)NN * LATD * 2);
    ushort_t* nmsgb  = (ushort_t*)alloc((size_t)NN * LATD * 2);
    ushort_t* sn_bf  = (ushort_t*)alloc((size_t)NC * LATD * 2);
    ushort_t* Wc1t = (ushort_t*)alloc((size_t)LATD * HIDD * 2);
    ushort_t* Wc2t = (ushort_t*)alloc((size_t)HIDD * HIDD * 2);
    ushort_t* Wn1t = (ushort_t*)alloc((size_t)LATD * HIDD * 2);
    ushort_t* Wn2t = (ushort_t*)alloc((size_t)HIDD * LATD * 2);
    ushort_t* We1t = (ushort_t*)alloc((size_t)2 * LATD * HIDD * 2);
    ushort_t* We2t = (ushort_t*)alloc((size_t)HIDD * LATD * 2);

    cur = (cur + 63) & ~(uintptr_t)63;
    size_t rem_bytes = (wend > cur) ? (size_t)(wend - cur) : 0;
    size_t chunk_sz = (rem_bytes / (2 * (size_t)HIDD * 2)) & ~(size_t)127;
    if (chunk_sz > 51200) chunk_sz = 51200;
    if (chunk_sz < 256) return;  // fail soft
    const int CH = (int)chunk_sz;
    ushort_t* bufA = (ushort_t*)cur;
    ushort_t* bufB = bufA + (size_t)CH * HIDD;

    hipMemsetAsync(zbase, 0, zero_bytes, stream);

    dim3 blk(256);

    // ---- prep: input/weight conversions ----
    conv_f2b_kernel<<<2048, blk, 0, stream>>>(emb_nodes, xemb, (long)NN * LATD);
    conv_f2b_kernel<<<2048, blk, 0, stream>>>(enc_nodes, xenc, (long)NN * LATD);
    transpose_conv_kernel<<<(LATD * HIDD + 255) / 256, blk, 0, stream>>>(Wc1, Wc1t, LATD, HIDD);
    transpose_conv_kernel<<<(HIDD * HIDD + 255) / 256, blk, 0, stream>>>(Wc2, Wc2t, HIDD, HIDD);
    transpose_conv_kernel<<<(LATD * HIDD + 255) / 256, blk, 0, stream>>>(Wn1, Wn1t, LATD, HIDD);
    transpose_conv_kernel<<<(HIDD * LATD + 255) / 256, blk, 0, stream>>>(Wn2, Wn2t, HIDD, LATD);
    transpose_conv_kernel<<<(2 * LATD * HIDD + 255) / 256, blk, 0, stream>>>(We1, We1t, 2 * LATD, HIDD);
    transpose_conv_kernel<<<(HIDD * LATD + 255) / 256, blk, 0, stream>>>(We2, We2t, HIDD, LATD);

    // ---- fused node chain, chunked: xemb->h1->h2->embeddings ----
    for (int m0 = 0; m0 < NN; m0 += CH) {
        int cm = (NN - m0 < CH) ? (NN - m0) : CH;
        gemm_mfma<ACT_TANH, false, true><<<dim3(HIDD / 128, (cm + 127) / 128), blk, 0, stream>>>(
            xemb + (size_t)m0 * LATD, Wc1t, bc1, bufA, cm, HIDD, LATD, nullptr, nullptr, nullptr);
        gemm_mfma<ACT_TANH, false, true><<<dim3(HIDD / 128, (cm + 127) / 128), blk, 0, stream>>>(
            bufA, Wc2t, bc2, bufB, cm, HIDD, HIDD, nullptr, nullptr, nullptr);
        emb_kernel<<<(cm + 255) / 256, blk, 0, stream>>>(
            bufB, Wc3, bc3, out_emb + (size_t)m0 * EMBD, cm);
    }

    // ---- cluster means ----
    cluster_accum<<<(NN + 255) / 256, blk, 0, stream>>>(out_emb, clusters, csums, ccnt);
    means_kernel<<<(NC + 255) / 256, blk, 0, stream>>>(csums, ccnt, means);

    // ---- super edge weights (4 edges/thread) ----
    sg_lik_kernel<<<(NES / 4 + 255) / 256, blk, 0, stream>>>(means, sg0, sg1, sg_lik, stats);
    sgw_kernel<<<(NES / 4 + 255) / 256, blk, 0, stream>>>(sg_lik, stats, sg_gamma, sg_beta, out_sew);

    // ---- bipartite edge weights (hist fused; 4 edges/thread) ----
    bg_lik_kernel<<<(NEB / 4 + 255) / 256, blk, 0, stream>>>(out_emb, means, bg_src, bg_dst, bg_lik, stats, cnt);
    bw_kernel<<<(NEB / 4 + 255) / 256, blk, 0, stream>>>(bg_lik, stats, bg_gamma, bg_beta, bg_src, bwv, denom);
    bw_norm_kernel<<<(NEB / 4 + 255) / 256, blk, 0, stream>>>(bwv, denom, bg_src, out_bw);

    // ---- counting sort of edges by destination cluster ----
    scan_kernel<<<1, 1024, 0, stream>>>(cnt, offs, NC);
    scatter_kernel<<<(NEB / 4 + 255) / 256, blk, 0, stream>>>(bg_dst, offs, fill, eids);

    // ---- node messages, chunked: xenc->nm->nmsg(bf16, full) ----
    for (int m0 = 0; m0 < NN; m0 += CH) {
        int cm = (NN - m0 < CH) ? (NN - m0) : CH;
        gemm_mfma<ACT_RELU, false, true><<<dim3(HIDD / 128, (cm + 127) / 128), blk, 0, stream>>>(
            xenc + (size_t)m0 * LATD, Wn1t, cn1, bufA, cm, HIDD, LATD, nullptr, nullptr, nullptr);
        gemm_mfma<ACT_RELU, false, true><<<dim3(LATD / 128, (cm + 127) / 128), blk, 0, stream>>>(
            bufA, Wn2t, cn2, nmsgb + (size_t)m0 * LATD, cm, LATD, HIDD, nullptr, nullptr, nullptr);
    }

    // ---- supernodes (sorted edge lists, no atomics) ----
    supernodes_kernel<<<NC, 128, 0, stream>>>(nmsgb, bwv, bg_src, eids, offs, out_sn);
    conv_f2b_kernel<<<512, blk, 0, stream>>>(out_sn, sn_bf, (long)NC * LATD);

    // ---- superedges, chunked (bufA+bufB = one 2*CH-row region) ----
    const int CE = 2 * CH;
    for (int e0 = 0; e0 < NES; e0 += CE) {
        int ce = (NES - e0 < CE) ? (NES - e0) : CE;
        gemm_mfma<ACT_RELU, true, true><<<dim3(HIDD / 128, (ce + 127) / 128), blk, 0, stream>>>(
            nullptr, We1t, ce1, bufA, ce, HIDD, 2 * LATD, sg0 + e0, sg1 + e0, sn_bf);
        gemm_mfma<ACT_RELU, false, false><<<dim3(LATD / 128, (ce + 127) / 128), blk, 0, stream>>>(
            bufA, We2t, ce2, out_se + (size_t)e0 * LATD, ce, LATD, HIDD, nullptr, nullptr, nullptr);
    }
}

// Round 8
// 981.131 us; speedup vs baseline: 1.1355x; 1.0427x over previous
//
#include <hip/hip_runtime.h>
#include <cstdint>
#include <cstddef>

// Problem constants (SuperGraphConstruction)
#define NN 100000      // nodes
#define NC 20000       // clusters
#define LATD 128
#define HIDD 512
#define EMBD 12
#define NES 160000     // super edges
#define NEB 800000     // bipartite edges

enum { ACT_NONE = 0, ACT_TANH = 1, ACT_RELU = 2 };

typedef __attribute__((ext_vector_type(8))) short bf16x8;
typedef __attribute__((ext_vector_type(4))) float f32x4;
typedef unsigned short ushort_t;

__device__ __forceinline__ float fast_tanh(float x) {
    return 1.f - 2.f / (__expf(2.f * x) + 1.f);
}
__device__ __forceinline__ ushort_t f2bf(float f) {
    union { float f; unsigned u; } x; x.f = f;
    unsigned r = x.u + 0x7FFFu + ((x.u >> 16) & 1u);  // RNE
    return (ushort_t)(r >> 16);
}
__device__ __forceinline__ float bf2f(ushort_t h) {
    union { unsigned u; float f; } x; x.u = ((unsigned)h) << 16;
    return x.f;
}

typedef __attribute__((address_space(1))) void gvoid_t;
typedef __attribute__((address_space(3))) void svoid_t;
__device__ __forceinline__ void gload_lds16(const void* g, void* l) {
    // async global->LDS, 16B/lane; LDS dest = wave-uniform base + lane*16
    __builtin_amdgcn_global_load_lds((gvoid_t*)g, (svoid_t*)l, 16, 0, 0);
}

// ---------------------------------------------------------------------------
// fp32 -> bf16 elementwise (n multiple of 8 assumed at call sites)
// ---------------------------------------------------------------------------
__global__ __launch_bounds__(256) void conv_f2b_kernel(
    const float* __restrict__ in, ushort_t* __restrict__ out, long n)
{
    long i = ((long)blockIdx.x * 256 + threadIdx.x) * 8;
    long stride = (long)gridDim.x * 256 * 8;
    for (; i + 7 < n; i += stride) {
        float4 a = *(const float4*)(in + i);
        float4 b = *(const float4*)(in + i + 4);
        ushort_t o[8] = { f2bf(a.x), f2bf(a.y), f2bf(a.z), f2bf(a.w),
                          f2bf(b.x), f2bf(b.y), f2bf(b.z), f2bf(b.w) };
        *(int4*)(out + i) = *(int4*)o;
    }
}

// W [K][N] fp32 -> Wt [N][K] bf16  (small, launched per weight)
__global__ __launch_bounds__(256) void transpose_conv_kernel(
    const float* __restrict__ W, ushort_t* __restrict__ Wt, int K, int N)
{
    int i = blockIdx.x * 256 + threadIdx.x;
    if (i >= K * N) return;
    int n = i / K, k = i % K;
    Wt[i] = f2bf(W[(size_t)k * N + n]);
}

// ---------------------------------------------------------------------------
// bf16 MFMA GEMM (m97 structure + T2 XOR swizzle): C = act(A @ B + bias)
//   A bf16 row-major [M][K]; Bt bf16 PRE-TRANSPOSED [N][K]; bias fp32.
//   GATHER: A row m = concat(gsrc[g0[m]][0:128], gsrc[g1[m]][0:128]), K=256.
//   BM=BN=128, BK=64; 256 threads = 4 waves (2x2); each wave 64x64 out.
//   LDS linear [128][64]; both-sides XOR swizzle (rule #21): slot p of row r
//   holds data segment p^(r&7); staging pre-swizzles the GLOBAL source
//   segment, fragment reads XOR the slot with (row&7). 2-way max (free).
// ---------------------------------------------------------------------------
template<int ACT, bool GATHER, bool OUT_BF16>
__global__ __launch_bounds__(256) void gemm_mfma(
    const ushort_t* __restrict__ A, const ushort_t* __restrict__ Bt,
    const float* __restrict__ bias, void* __restrict__ Cv,
    int M, int N, int K,
    const int* __restrict__ g0, const int* __restrict__ g1,
    const ushort_t* __restrict__ gsrc)
{
    __shared__ ushort_t As[128 * 64];   // linear: row*64 + slot*8, swizzled data
    __shared__ ushort_t Bs[128 * 64];

    const int tid = threadIdx.x;
    const int m0 = blockIdx.y * 128, n0 = blockIdx.x * 128;
    const int w = tid >> 6, lane = tid & 63;
    const int wm = w >> 1, wn = w & 1;
    const int lr = lane & 15, lg = lane >> 4;
    const int lrow = lane >> 3;                    // 0..7 row within 8-row chunk
    const int seg  = (lane & 7) ^ lrow;            // inverse-swizzled source segment
    const int lcol = seg * 8;                      // bf16 col of that segment

    f32x4 acc[4][4];
#pragma unroll
    for (int i = 0; i < 4; ++i)
#pragma unroll
        for (int j = 0; j < 4; ++j) acc[i][j] = (f32x4){0.f, 0.f, 0.f, 0.f};

    for (int k0 = 0; k0 < K; k0 += 64) {
        // ---- stage tiles: each wave issues 4 A-chunks + 4 B-chunks (1KB each)
#pragma unroll
        for (int i = 0; i < 4; ++i) {
            int c = w * 4 + i;            // chunk 0..15 (8 rows each)
            int row = c * 8 + lrow;       // tile row 0..127  (row&7 == lrow)
            int gm = m0 + row; if (gm >= M) gm = M - 1;  // clamp tail
            const ushort_t* ga;
            if (!GATHER) {
                ga = A + (size_t)gm * K + k0 + lcol;
            } else {
                int src = (k0 >= LATD) ? g1[gm] : g0[gm];
                ga = gsrc + (size_t)src * LATD + (k0 & (LATD - 1)) + lcol;
            }
            gload_lds16(ga, As + c * 512);
            const ushort_t* gb = Bt + (size_t)(n0 + row) * K + k0 + lcol;
            gload_lds16(gb, Bs + c * 512);
        }
        __syncthreads();

        // ---- 2 k-steps of 32 (reads XOR slot with row&7) ----
#pragma unroll
        for (int ks = 0; ks < 2; ++ks) {
            bf16x8 af[4], bf[4];
#pragma unroll
            for (int mt = 0; mt < 4; ++mt) {
                int row = wm * 64 + mt * 16 + lr;
                int slot = (ks * 4 + lg) ^ (row & 7);
                af[mt] = *(const bf16x8*)&As[row * 64 + slot * 8];
            }
#pragma unroll
            for (int nt = 0; nt < 4; ++nt) {
                int row = wn * 64 + nt * 16 + lr;
                int slot = (ks * 4 + lg) ^ (row & 7);
                bf[nt] = *(const bf16x8*)&Bs[row * 64 + slot * 8];
            }
#pragma unroll
            for (int mt = 0; mt < 4; ++mt)
#pragma unroll
                for (int nt = 0; nt < 4; ++nt)
                    acc[mt][nt] = __builtin_amdgcn_mfma_f32_16x16x32_bf16(
                        af[mt], bf[nt], acc[mt][nt], 0, 0, 0);
        }
        __syncthreads();
    }

    // ---- epilogue: D lane,reg -> row=(lane>>4)*4+reg, col=lane&15 ----
#pragma unroll
    for (int nt = 0; nt < 4; ++nt) {
        int col = n0 + wn * 64 + nt * 16 + lr;
        float bv = bias[col];
#pragma unroll
        for (int mt = 0; mt < 4; ++mt) {
#pragma unroll
            for (int r = 0; r < 4; ++r) {
                int row = m0 + wm * 64 + mt * 16 + lg * 4 + r;
                if (row >= M) continue;
                float v = acc[mt][nt][r] + bv;
                if (ACT == ACT_TANH) v = fast_tanh(v);
                else if (ACT == ACT_RELU) v = fmaxf(v, 0.f);
                if (OUT_BF16) ((ushort_t*)Cv)[(size_t)row * N + col] = f2bf(v);
                else ((float*)Cv)[(size_t)row * N + col] = v;
            }
        }
    }
}

// ---------------------------------------------------------------------------
// embeddings = l2norm(h2 @ Wc3 + bc3); THREAD-per-row; h2 bf16.
// ---------------------------------------------------------------------------
__global__ __launch_bounds__(256) void emb_kernel(
    const ushort_t* __restrict__ h2, const float* __restrict__ W,  // [512][12]
    const float* __restrict__ bias, float* __restrict__ out, int M)
{
    __shared__ float Wl[HIDD * EMBD];  // same layout as W (row-major [k][j])
    for (int i = threadIdx.x; i < HIDD * EMBD; i += 256) Wl[i] = W[i];
    __syncthreads();

    int m = blockIdx.x * 256 + threadIdx.x;
    if (m >= M) return;
    const ushort_t* row = h2 + (size_t)m * HIDD;

    float acc[EMBD] = {};
#pragma unroll 2
    for (int k0 = 0; k0 < HIDD; k0 += 8) {
        bf16x8 v = *(const bf16x8*)(row + k0);
        float f[8];
#pragma unroll
        for (int u = 0; u < 8; ++u) f[u] = bf2f((ushort_t)v[u]);
#pragma unroll
        for (int u = 0; u < 8; ++u) {
            const float* wr = &Wl[(k0 + u) * EMBD];
#pragma unroll
            for (int j = 0; j < EMBD; ++j) acc[j] += f[u] * wr[j];
        }
    }
    float vv[EMBD];
    float ss = 0.f;
#pragma unroll
    for (int j = 0; j < EMBD; ++j) { vv[j] = acc[j] + bias[j]; ss += vv[j] * vv[j]; }
    float inv = 1.f / fmaxf(sqrtf(ss), 1e-12f);
#pragma unroll
    for (int j = 0; j < EMBD; ++j) out[(size_t)m * EMBD + j] = vv[j] * inv;
}

// ---------------------------------------------------------------------------
// cluster sums + counts: thread-per-node, float4 row loads
// ---------------------------------------------------------------------------
__global__ void cluster_accum(const float* __restrict__ emb,
                              const int* __restrict__ clusters,
                              float* __restrict__ csums, float* __restrict__ ccnt)
{
    int n = blockIdx.x * 256 + threadIdx.x;
    if (n >= NN) return;
    int c = clusters[n];
    const float4* row = (const float4*)(emb + (size_t)n * EMBD);
    float4 r0 = row[0], r1 = row[1], r2 = row[2];
    float* dst = &csums[(size_t)c * EMBD];
    atomicAdd(&dst[0], r0.x);  atomicAdd(&dst[1], r0.y);
    atomicAdd(&dst[2], r0.z);  atomicAdd(&dst[3], r0.w);
    atomicAdd(&dst[4], r1.x);  atomicAdd(&dst[5], r1.y);
    atomicAdd(&dst[6], r1.z);  atomicAdd(&dst[7], r1.w);
    atomicAdd(&dst[8], r2.x);  atomicAdd(&dst[9], r2.y);
    atomicAdd(&dst[10], r2.z); atomicAdd(&dst[11], r2.w);
    atomicAdd(&ccnt[c], 1.f);
}

__global__ void means_kernel(const float* __restrict__ csums,
                             const float* __restrict__ ccnt,
                             float* __restrict__ means)
{
    int c = blockIdx.x * 256 + threadIdx.x;
    if (c >= NC) return;
    float cv = fmaxf(ccnt[c], 1.f);
    float v[EMBD];
    float ss = 0.f;
#pragma unroll
    for (int j = 0; j < EMBD; ++j) {
        v[j] = csums[(size_t)c * EMBD + j] / cv;
        ss += v[j] * v[j];
    }
    float inv = 1.f / fmaxf(sqrtf(ss), 1e-12f);
#pragma unroll
    for (int j = 0; j < EMBD; ++j) means[(size_t)c * EMBD + j] = v[j] * inv;
}

// ---------------------------------------------------------------------------
// block-reduced sum/sumsq (pre-accumulated per-thread) -> atomics
// ---------------------------------------------------------------------------
__device__ __forceinline__ void block_stats2(float x, float x2, float* s_sum, float* s_sumsq)
{
#pragma unroll
    for (int s = 32; s >= 1; s >>= 1) {
        x += __shfl_xor(x, s, 64);
        x2 += __shfl_xor(x2, s, 64);
    }
    __shared__ float w0[4], w1[4];
    int lane = threadIdx.x & 63, w = threadIdx.x >> 6;
    if (lane == 0) { w0[w] = x; w1[w] = x2; }
    __syncthreads();
    if (threadIdx.x == 0) {
        float a = 0.f, b = 0.f;
        for (int i = 0; i < 4; ++i) { a += w0[i]; b += w1[i]; }
        atomicAdd(s_sum, a);
        atomicAdd(s_sumsq, b);
    }
}

// ---------------------------------------------------------------------------
// sg_lik, 4 edges/thread (NES % 4 == 0)
// ---------------------------------------------------------------------------
__global__ __launch_bounds__(256) void sg_lik_kernel(
    const float* __restrict__ means, const int* __restrict__ sg0,
    const int* __restrict__ sg1, float* __restrict__ sg_lik, float* __restrict__ stats)
{
    int base = (blockIdx.x * 256 + threadIdx.x) * 4;
    float xs = 0.f, xs2 = 0.f;
    if (base < NES) {
        int4 a4 = *(const int4*)(sg0 + base);
        int4 b4 = *(const int4*)(sg1 + base);
        int ai[4] = {a4.x, a4.y, a4.z, a4.w};
        int bi[4] = {b4.x, b4.y, b4.z, b4.w};
        float4 av[4][3], bv[4][3];
#pragma unroll
        for (int i = 0; i < 4; ++i) {
            const float4* ap = (const float4*)(means + (size_t)ai[i] * EMBD);
            const float4* bp = (const float4*)(means + (size_t)bi[i] * EMBD);
            av[i][0] = ap[0]; av[i][1] = ap[1]; av[i][2] = ap[2];
            bv[i][0] = bp[0]; bv[i][1] = bp[1]; bv[i][2] = bp[2];
        }
        float4 o;
        float* op = (float*)&o;
#pragma unroll
        for (int i = 0; i < 4; ++i) {
            float s = av[i][0].x * bv[i][0].x + av[i][0].y * bv[i][0].y
                    + av[i][0].z * bv[i][0].z + av[i][0].w * bv[i][0].w
                    + av[i][1].x * bv[i][1].x + av[i][1].y * bv[i][1].y
                    + av[i][1].z * bv[i][1].z + av[i][1].w * bv[i][1].w
                    + av[i][2].x * bv[i][2].x + av[i][2].y * bv[i][2].y
                    + av[i][2].z * bv[i][2].z + av[i][2].w * bv[i][2].w;
            op[i] = s;
            xs += s; xs2 += s * s;
        }
        *(float4*)(sg_lik + base) = o;
    }
    block_stats2(xs, xs2, &stats[0], &stats[1]);
}

__global__ __launch_bounds__(256) void sgw_kernel(
    const float* __restrict__ sg_lik, const float* __restrict__ stats,
    const float* __restrict__ gamma, const float* __restrict__ beta,
    float* __restrict__ out)
{
    int base = (blockIdx.x * 256 + threadIdx.x) * 4;
    if (base >= NES) return;
    float m = stats[0] / (float)NES;
    float var = stats[1] / (float)NES - m * m;
    float rs = rsqrtf(var + 1e-5f) * gamma[0];
    float4 v = *(const float4*)(sg_lik + base);
    float4 o;
    o.x = 1.f / (1.f + __expf(-((v.x - m) * rs + beta[0])));
    o.y = 1.f / (1.f + __expf(-((v.y - m) * rs + beta[0])));
    o.z = 1.f / (1.f + __expf(-((v.z - m) * rs + beta[0])));
    o.w = 1.f / (1.f + __expf(-((v.w - m) * rs + beta[0])));
    *(float4*)(out + base) = o;
}

// ---------------------------------------------------------------------------
// bg_lik + histogram, 4 edges/thread (NEB % 4 == 0)
// ---------------------------------------------------------------------------
__global__ __launch_bounds__(256) void bg_lik_kernel(
    const float* __restrict__ emb, const float* __restrict__ means,
    const int* __restrict__ bg_src, const int* __restrict__ bg_dst,
    float* __restrict__ bg_lik, float* __restrict__ stats, int* __restrict__ cnt)
{
    int base = (blockIdx.x * 256 + threadIdx.x) * 4;
    float xs = 0.f, xs2 = 0.f;
    if (base < NEB) {
        int4 s4 = *(const int4*)(bg_src + base);
        int4 d4 = *(const int4*)(bg_dst + base);
        int si[4] = {s4.x, s4.y, s4.z, s4.w};
        int di[4] = {d4.x, d4.y, d4.z, d4.w};
        float4 av[4][3], bv[4][3];
#pragma unroll
        for (int i = 0; i < 4; ++i) {
            const float4* ap = (const float4*)(emb + (size_t)si[i] * EMBD);
            const float4* bp = (const float4*)(means + (size_t)di[i] * EMBD);
            av[i][0] = ap[0]; av[i][1] = ap[1]; av[i][2] = ap[2];
            bv[i][0] = bp[0]; bv[i][1] = bp[1]; bv[i][2] = bp[2];
        }
#pragma unroll
        for (int i = 0; i < 4; ++i) atomicAdd(&cnt[di[i]], 1);
        float4 o;
        float* op = (float*)&o;
#pragma unroll
        for (int i = 0; i < 4; ++i) {
            float s = av[i][0].x * bv[i][0].x + av[i][0].y * bv[i][0].y
                    + av[i][0].z * bv[i][0].z + av[i][0].w * bv[i][0].w
                    + av[i][1].x * bv[i][1].x + av[i][1].y * bv[i][1].y
                    + av[i][1].z * bv[i][1].z + av[i][1].w * bv[i][1].w
                    + av[i][2].x * bv[i][2].x + av[i][2].y * bv[i][2].y
                    + av[i][2].z * bv[i][2].z + av[i][2].w * bv[i][2].w;
            op[i] = s;
            xs += s; xs2 += s * s;
        }
        *(float4*)(bg_lik + base) = o;
    }
    block_stats2(xs, xs2, &stats[2], &stats[3]);
}

__global__ __launch_bounds__(256) void bw_kernel(
    const float* __restrict__ bg_lik, const float* __restrict__ stats,
    const float* __restrict__ gamma, const float* __restrict__ beta,
    const int* __restrict__ bg_src, float* __restrict__ bw, float* __restrict__ denom)
{
    int base = (blockIdx.x * 256 + threadIdx.x) * 4;
    if (base >= NEB) return;
    float m = stats[2] / (float)NEB;
    float var = stats[3] / (float)NEB - m * m;
    float rs = rsqrtf(var + 1e-5f) * gamma[0];
    int4 s4 = *(const int4*)(bg_src + base);
    int si[4] = {s4.x, s4.y, s4.z, s4.w};
    float4 v = *(const float4*)(bg_lik + base);
    float vi[4] = {v.x, v.y, v.z, v.w};
    float4 o;
    float* op = (float*)&o;
#pragma unroll
    for (int i = 0; i < 4; ++i) {
        float w = __expf((vi[i] - m) * rs + beta[0]);
        op[i] = w;
        atomicAdd(&denom[si[i]], w);
    }
    *(float4*)(bw + base) = o;
}

__global__ __launch_bounds__(256) void bw_norm_kernel(
    float* __restrict__ bw, const float* __restrict__ denom,
    const int* __restrict__ bg_src, float* __restrict__ out)
{
    int base = (blockIdx.x * 256 + threadIdx.x) * 4;
    if (base >= NEB) return;
    int4 s4 = *(const int4*)(bg_src + base);
    int si[4] = {s4.x, s4.y, s4.z, s4.w};
    float dv[4];
#pragma unroll
    for (int i = 0; i < 4; ++i) dv[i] = denom[si[i]];
    float4 v = *(const float4*)(bw + base);
    float4 o;
    o.x = v.x / (1e-12f + dv[0]);
    o.y = v.y / (1e-12f + dv[1]);
    o.z = v.z / (1e-12f + dv[2]);
    o.w = v.w / (1e-12f + dv[3]);
    *(float4*)(bw + base) = o;
    *(float4*)(out + base) = o;
}

// ---------------------------------------------------------------------------
__global__ __launch_bounds__(1024) void scan_kernel(
    const int* __restrict__ cnt, int* __restrict__ offs, int C)
{
    __shared__ int wsum[16];
    __shared__ int carry_s, ctot_s;
    const int tid = threadIdx.x;
    const int lane = tid & 63, w = tid >> 6;
    if (tid == 0) carry_s = 0;
    __syncthreads();
    for (int base = 0; base < C; base += 1024) {
        int i = base + tid;
        int v = (i < C) ? cnt[i] : 0;
        int x = v;
#pragma unroll
        for (int s = 1; s < 64; s <<= 1) {
            int y = __shfl_up(x, s, 64);
            if (lane >= s) x += y;
        }
        if (lane == 63) wsum[w] = x;
        __syncthreads();
        if (tid == 0) {
            int s = 0;
            for (int k = 0; k < 16; ++k) { int t = wsum[k]; wsum[k] = s; s += t; }
            ctot_s = s;
        }
        __syncthreads();
        int excl = carry_s + wsum[w] + (x - v);
        if (i < C) offs[i] = excl;
        __syncthreads();
        if (tid == 0) carry_s += ctot_s;
        __syncthreads();
    }
    if (tid == 0) offs[C] = carry_s;
}

__global__ void scatter_kernel(const int* __restrict__ bg_dst,
                               const int* __restrict__ offs,
                               int* __restrict__ fill, int* __restrict__ eids)
{
    int base = (blockIdx.x * 256 + threadIdx.x) * 4;
    if (base >= NEB) return;
    int4 d4 = *(const int4*)(bg_dst + base);
    int di[4] = {d4.x, d4.y, d4.z, d4.w};
#pragma unroll
    for (int i = 0; i < 4; ++i) {
        int p = atomicAdd(&fill[di[i]], 1);
        eids[offs[di[i]] + p] = base + i;
    }
}

// ---------------------------------------------------------------------------
// supernodes[c][:] = sum_{e: bg_dst[e]==c} bw[e]*nmsg[bg_src[e]][:]  (nmsg bf16)
// 256 threads = 4 waves; within a wave, 16 lanes x 16B cover one 256B row,
// so ONE vmem instruction fetches 4 edges (1KB in flight). Waves split the
// edge list; shfl_xor(16,32) folds edge slots, 4x128 LDS folds waves.
// ---------------------------------------------------------------------------
__global__ __launch_bounds__(256) void supernodes_kernel(
    const ushort_t* __restrict__ nmsg, const float* __restrict__ bw,
    const int* __restrict__ bg_src, const int* __restrict__ eids,
    const int* __restrict__ offs, float* __restrict__ sn)
{
    __shared__ float red[4][LATD];
    const int c = blockIdx.x;
    const int tid = threadIdx.x;
    const int wv = tid >> 6, lane = tid & 63;
    const int er = lane >> 4;        // edge slot 0..3 within wave
    const int cg = lane & 15;        // column group: cols [cg*8, cg*8+8)
    const int beg = offs[c], end = offs[c + 1];

    float acc[8] = {};
    for (int p = beg + wv * 4 + er; p < end; p += 16) {
        int e = eids[p];             // broadcast across the 16 cg-lanes
        int s = bg_src[e];
        float w = bw[e];
        bf16x8 v = *(const bf16x8*)(nmsg + (size_t)s * LATD + cg * 8);
#pragma unroll
        for (int j = 0; j < 8; ++j) acc[j] += w * bf2f((ushort_t)v[j]);
    }
    // fold the 4 edge slots within the wave (lanes same cg, er 0..3)
#pragma unroll
    for (int j = 0; j < 8; ++j) {
        acc[j] += __shfl_xor(acc[j], 16, 64);
        acc[j] += __shfl_xor(acc[j], 32, 64);
    }
    if (lane < 16) {
        *(float4*)&red[wv][cg * 8]     = (float4){acc[0], acc[1], acc[2], acc[3]};
        *(float4*)&red[wv][cg * 8 + 4] = (float4){acc[4], acc[5], acc[6], acc[7]};
    }
    __syncthreads();
    if (tid < LATD) {
        float s = red[0][tid] + red[1][tid] + red[2][tid] + red[3][tid];
        sn[(size_t)c * LATD + tid] = s;
    }
}

// ---------------------------------------------------------------------------
extern "C" void kernel_launch(void* const* d_in, const int* in_sizes, int n_in,
                              void* d_out, int out_size, void* d_ws, size_t ws_size,
                              hipStream_t stream)
{
    const float* emb_nodes = (const float*)d_in[0];
    const float* enc_nodes = (const float*)d_in[1];
    const float* Wc1 = (const float*)d_in[2];  const float* bc1 = (const float*)d_in[3];
    const float* Wc2 = (const float*)d_in[4];  const float* bc2 = (const float*)d_in[5];
    const float* Wc3 = (const float*)d_in[6];  const float* bc3 = (const float*)d_in[7];
    const float* Wn1 = (const float*)d_in[8];  const float* cn1 = (const float*)d_in[9];
    const float* Wn2 = (const float*)d_in[10]; const float* cn2 = (const float*)d_in[11];
    const float* We1 = (const float*)d_in[12]; const float* ce1 = (const float*)d_in[13];
    const float* We2 = (const float*)d_in[14]; const float* ce2 = (const float*)d_in[15];
    const float* sg_gamma = (const float*)d_in[16]; const float* sg_beta = (const float*)d_in[17];
    const float* bg_gamma = (const float*)d_in[18]; const float* bg_beta = (const float*)d_in[19];
    const int* clusters = (const int*)d_in[20];
    const int* sg0 = (const int*)d_in[21];
    const int* sg1 = sg0 + NES;
    const int* bg_src = (const int*)d_in[22];
    const int* bg_dst = (const int*)d_in[23];

    // output layout (flat, return order)
    float* out_emb = (float*)d_out;                       // NN*EMBD
    float* out_sn  = out_emb + (size_t)NN * EMBD;         // NC*LATD
    float* out_se  = out_sn + (size_t)NC * LATD;          // NES*LATD
    float* out_bw  = out_se + (size_t)NES * LATD;         // NEB
    float* out_sew = out_bw + (size_t)NEB;                // NES

    // ---------------- workspace layout (byte cursor, 64B-aligned) ----------
    uintptr_t cur = (uintptr_t)d_ws;
    uintptr_t wend = cur + ws_size;
    auto alloc = [&](size_t bytes) -> void* {
        cur = (cur + 63) & ~(uintptr_t)63;
        void* p = (void*)cur;
        cur += bytes;
        return p;
    };

    // zeroed region (contiguous)
    float* zbase = (float*)alloc(((size_t)NC * EMBD + NC + NN + 8 + NC + NC) * 4);
    float* csums = zbase;
    float* ccnt  = csums + (size_t)NC * EMBD;
    float* denom = ccnt + NC;
    float* stats = denom + NN;
    int*   cnt   = (int*)(stats + 8);
    int*   fill  = cnt + NC;
    size_t zero_bytes = ((size_t)NC * EMBD + NC + NN + 8 + NC + NC) * 4;

    float* means  = (float*)alloc((size_t)NC * EMBD * 4);
    float* sg_lik = (float*)alloc((size_t)NES * 4);
    float* bg_lik = (float*)alloc((size_t)NEB * 4);
    float* bwv    = (float*)alloc((size_t)NEB * 4);
    int*   offs   = (int*)alloc((size_t)(NC + 1) * 4);
    int*   eids   = (int*)alloc((size_t)NEB * 4);

    ushort_t* xemb   = (ushort_t*)alloc((size_t)NN * LATD * 2);
    ushort_t* xenc   = (ushort_t*)alloc((size_t)NN * LATD * 2);
    ushort_t* nmsgb  = (ushort_t*)alloc((size_t)NN * LATD * 2);
    ushort_t* sn_bf  = (ushort_t*)alloc((size_t)NC * LATD * 2);
    ushort_t* Wc1t = (ushort_t*)alloc((size_t)LATD * HIDD * 2);
    ushort_t* Wc2t = (ushort_t*)alloc((size_t)HIDD * HIDD * 2);
    ushort_t* Wn1t = (ushort_t*)alloc((size_t)LATD * HIDD * 2);
    ushort_t* Wn2t = (ushort_t*)alloc((size_t)HIDD * LATD * 2);
    ushort_t* We1t = (ushort_t*)alloc((size_t)2 * LATD * HIDD * 2);
    ushort_t* We2t = (ushort_t*)alloc((size_t)HIDD * LATD * 2);

    cur = (cur + 63) & ~(uintptr_t)63;
    size_t rem_bytes = (wend > cur) ? (size_t)(wend - cur) : 0;
    size_t chunk_sz = (rem_bytes / (2 * (size_t)HIDD * 2)) & ~(size_t)127;
    if (chunk_sz > 51200) chunk_sz = 51200;
    if (chunk_sz < 256) return;  // fail soft
    const int CH = (int)chunk_sz;
    ushort_t* bufA = (ushort_t*)cur;
    ushort_t* bufB = bufA + (size_t)CH * HIDD;

    hipMemsetAsync(zbase, 0, zero_bytes, stream);

    dim3 blk(256);

    // ---- prep: input/weight conversions ----
    conv_f2b_kernel<<<2048, blk, 0, stream>>>(emb_nodes, xemb, (long)NN * LATD);
    conv_f2b_kernel<<<2048, blk, 0, stream>>>(enc_nodes, xenc, (long)NN * LATD);
    transpose_conv_kernel<<<(LATD * HIDD + 255) / 256, blk, 0, stream>>>(Wc1, Wc1t, LATD, HIDD);
    transpose_conv_kernel<<<(HIDD * HIDD + 255) / 256, blk, 0, stream>>>(Wc2, Wc2t, HIDD, HIDD);
    transpose_conv_kernel<<<(LATD * HIDD + 255) / 256, blk, 0, stream>>>(Wn1, Wn1t, LATD, HIDD);
    transpose_conv_kernel<<<(HIDD * LATD + 255) / 256, blk, 0, stream>>>(Wn2, Wn2t, HIDD, LATD);
    transpose_conv_kernel<<<(2 * LATD * HIDD + 255) / 256, blk, 0, stream>>>(We1, We1t, 2 * LATD, HIDD);
    transpose_conv_kernel<<<(HIDD * LATD + 255) / 256, blk, 0, stream>>>(We2, We2t, HIDD, LATD);

    // ---- fused node chain, chunked: xemb->h1->h2->embeddings ----
    for (int m0 = 0; m0 < NN; m0 += CH) {
        int cm = (NN - m0 < CH) ? (NN - m0) : CH;
        gemm_mfma<ACT_TANH, false, true><<<dim3(HIDD / 128, (cm + 127) / 128), blk, 0, stream>>>(
            xemb + (size_t)m0 * LATD, Wc1t, bc1, bufA, cm, HIDD, LATD, nullptr, nullptr, nullptr);
        gemm_mfma<ACT_TANH, false, true><<<dim3(HIDD / 128, (cm + 127) / 128), blk, 0, stream>>>(
            bufA, Wc2t, bc2, bufB, cm, HIDD, HIDD, nullptr, nullptr, nullptr);
        emb_kernel<<<(cm + 255) / 256, blk, 0, stream>>>(
            bufB, Wc3, bc3, out_emb + (size_t)m0 * EMBD, cm);
    }

    // ---- cluster means ----
    cluster_accum<<<(NN + 255) / 256, blk, 0, stream>>>(out_emb, clusters, csums, ccnt);
    means_kernel<<<(NC + 255) / 256, blk, 0, stream>>>(csums, ccnt, means);

    // ---- super edge weights (4 edges/thread) ----
    sg_lik_kernel<<<(NES / 4 + 255) / 256, blk, 0, stream>>>(means, sg0, sg1, sg_lik, stats);
    sgw_kernel<<<(NES / 4 + 255) / 256, blk, 0, stream>>>(sg_lik, stats, sg_gamma, sg_beta, out_sew);

    // ---- bipartite edge weights (hist fused; 4 edges/thread) ----
    bg_lik_kernel<<<(NEB / 4 + 255) / 256, blk, 0, stream>>>(out_emb, means, bg_src, bg_dst, bg_lik, stats, cnt);
    bw_kernel<<<(NEB / 4 + 255) / 256, blk, 0, stream>>>(bg_lik, stats, bg_gamma, bg_beta, bg_src, bwv, denom);
    bw_norm_kernel<<<(NEB / 4 + 255) / 256, blk, 0, stream>>>(bwv, denom, bg_src, out_bw);

    // ---- counting sort of edges by destination cluster ----
    scan_kernel<<<1, 1024, 0, stream>>>(cnt, offs, NC);
    scatter_kernel<<<(NEB / 4 + 255) / 256, blk, 0, stream>>>(bg_dst, offs, fill, eids);

    // ---- node messages, chunked: xenc->nm->nmsg(bf16, full) ----
    for (int m0 = 0; m0 < NN; m0 += CH) {
        int cm = (NN - m0 < CH) ? (NN - m0) : CH;
        gemm_mfma<ACT_RELU, false, true><<<dim3(HIDD / 128, (cm + 127) / 128), blk, 0, stream>>>(
            xenc + (size_t)m0 * LATD, Wn1t, cn1, bufA, cm, HIDD, LATD, nullptr, nullptr, nullptr);
        gemm_mfma<ACT_RELU, false, true><<<dim3(LATD / 128, (cm + 127) / 128), blk, 0, stream>>>(
            bufA, Wn2t, cn2, nmsgb + (size_t)m0 * LATD, cm, LATD, HIDD, nullptr, nullptr, nullptr);
    }

    // ---- supernodes (sorted edge lists, no atomics; lane-packed gather) ----
    supernodes_kernel<<<NC, blk, 0, stream>>>(nmsgb, bwv, bg_src, eids, offs, out_sn);
    conv_f2b_kernel<<<512, blk, 0, stream>>>(out_sn, sn_bf, (long)NC * LATD);

    // ---- superedges, chunked (bufA+bufB = one 2*CH-row region) ----
    const int CE = 2 * CH;
    for (int e0 = 0; e0 < NES; e0 += CE) {
        int ce = (NES - e0 < CE) ? (NES - e0) : CE;
        gemm_mfma<ACT_RELU, true, true><<<dim3(HIDD / 128, (ce + 127) / 128), blk, 0, stream>>>(
            nullptr, We1t, ce1, bufA, ce, HIDD, 2 * LATD, sg0 + e0, sg1 + e0, sn_bf);
        gemm_mfma<ACT_RELU, false, false><<<dim3(LATD / 128, (ce + 127) / 128), blk, 0, stream>>>(
            bufA, We2t, ce2, out_se + (size_t)e0 * LATD, ce, LATD, HIDD, nullptr, nullptr, nullptr);
    }
}

// Round 9
// 929.470 us; speedup vs baseline: 1.1986x; 1.0556x over previous
//
#include <hip/hip_runtime.h>
#include <cstdint>
#include <cstddef>

// Problem constants (SuperGraphConstruction)
#define NN 100000      // nodes
#define NC 20000       // clusters
#define LATD 128
#define HIDD 512
#define EMBD 12
#define NES 160000     // super edges
#define NEB 800000     // bipartite edges

enum { ACT_NONE = 0, ACT_TANH = 1, ACT_RELU = 2 };

typedef __attribute__((ext_vector_type(8))) short bf16x8;
typedef __attribute__((ext_vector_type(4))) float f32x4;
typedef unsigned short ushort_t;

__device__ __forceinline__ float fast_tanh(float x) {
    return 1.f - 2.f / (__expf(2.f * x) + 1.f);
}
__device__ __forceinline__ ushort_t f2bf(float f) {
    union { float f; unsigned u; } x; x.f = f;
    unsigned r = x.u + 0x7FFFu + ((x.u >> 16) & 1u);  // RNE
    return (ushort_t)(r >> 16);
}
__device__ __forceinline__ float bf2f(ushort_t h) {
    union { unsigned u; float f; } x; x.u = ((unsigned)h) << 16;
    return x.f;
}

typedef __attribute__((address_space(1))) void gvoid_t;
typedef __attribute__((address_space(3))) void svoid_t;
__device__ __forceinline__ void gload_lds16(const void* g, void* l) {
    // async global->LDS, 16B/lane; LDS dest = wave-uniform base + lane*16
    __builtin_amdgcn_global_load_lds((gvoid_t*)g, (svoid_t*)l, 16, 0, 0);
}

// ---------------------------------------------------------------------------
// fp32 -> bf16 elementwise
// ---------------------------------------------------------------------------
__global__ __launch_bounds__(256) void conv_f2b_kernel(
    const float* __restrict__ in, ushort_t* __restrict__ out, long n)
{
    long i = ((long)blockIdx.x * 256 + threadIdx.x) * 8;
    long stride = (long)gridDim.x * 256 * 8;
    for (; i + 7 < n; i += stride) {
        float4 a = *(const float4*)(in + i);
        float4 b = *(const float4*)(in + i + 4);
        ushort_t o[8] = { f2bf(a.x), f2bf(a.y), f2bf(a.z), f2bf(a.w),
                          f2bf(b.x), f2bf(b.y), f2bf(b.z), f2bf(b.w) };
        *(int4*)(out + i) = *(int4*)o;
    }
}

// W [K][N] fp32 -> Wt [N][K] bf16
__global__ __launch_bounds__(256) void transpose_conv_kernel(
    const float* __restrict__ W, ushort_t* __restrict__ Wt, int K, int N)
{
    int i = blockIdx.x * 256 + threadIdx.x;
    if (i >= K * N) return;
    int n = i / K, k = i % K;
    Wt[i] = f2bf(W[(size_t)k * N + n]);
}

// ---------------------------------------------------------------------------
// bf16 MFMA GEMM (m97 + T2 swizzle), used for the node chain (G1, G2).
// ---------------------------------------------------------------------------
template<int ACT, bool OUT_BF16>
__global__ __launch_bounds__(256) void gemm_mfma(
    const ushort_t* __restrict__ A, const ushort_t* __restrict__ Bt,
    const float* __restrict__ bias, void* __restrict__ Cv,
    int M, int N, int K)
{
    __shared__ ushort_t As[128 * 64];   // linear: row*64 + slot*8, swizzled data
    __shared__ ushort_t Bs[128 * 64];

    const int tid = threadIdx.x;
    const int m0 = blockIdx.y * 128, n0 = blockIdx.x * 128;
    const int w = tid >> 6, lane = tid & 63;
    const int wm = w >> 1, wn = w & 1;
    const int lr = lane & 15, lg = lane >> 4;
    const int srow = lane >> 3;                    // 0..7 row within 8-row chunk
    const int sseg = (lane & 7) ^ srow;            // inverse-swizzled source segment

    f32x4 acc[4][4];
#pragma unroll
    for (int i = 0; i < 4; ++i)
#pragma unroll
        for (int j = 0; j < 4; ++j) acc[i][j] = (f32x4){0.f, 0.f, 0.f, 0.f};

    for (int k0 = 0; k0 < K; k0 += 64) {
#pragma unroll
        for (int i = 0; i < 4; ++i) {
            int c = w * 4 + i;
            int row = c * 8 + srow;
            int gm = m0 + row; if (gm >= M) gm = M - 1;
            gload_lds16(A + (size_t)gm * K + k0 + sseg * 8, As + c * 512);
            gload_lds16(Bt + (size_t)(n0 + row) * K + k0 + sseg * 8, Bs + c * 512);
        }
        __syncthreads();
#pragma unroll
        for (int ks = 0; ks < 2; ++ks) {
            bf16x8 af[4], bf[4];
#pragma unroll
            for (int mt = 0; mt < 4; ++mt) {
                int row = wm * 64 + mt * 16 + lr;
                int slot = (ks * 4 + lg) ^ (row & 7);
                af[mt] = *(const bf16x8*)&As[row * 64 + slot * 8];
            }
#pragma unroll
            for (int nt = 0; nt < 4; ++nt) {
                int row = wn * 64 + nt * 16 + lr;
                int slot = (ks * 4 + lg) ^ (row & 7);
                bf[nt] = *(const bf16x8*)&Bs[row * 64 + slot * 8];
            }
#pragma unroll
            for (int mt = 0; mt < 4; ++mt)
#pragma unroll
                for (int nt = 0; nt < 4; ++nt)
                    acc[mt][nt] = __builtin_amdgcn_mfma_f32_16x16x32_bf16(
                        af[mt], bf[nt], acc[mt][nt], 0, 0, 0);
        }
        __syncthreads();
    }

#pragma unroll
    for (int nt = 0; nt < 4; ++nt) {
        int col = n0 + wn * 64 + nt * 16 + lr;
        float bv = bias[col];
#pragma unroll
        for (int mt = 0; mt < 4; ++mt) {
#pragma unroll
            for (int r = 0; r < 4; ++r) {
                int row = m0 + wm * 64 + mt * 16 + lg * 4 + r;
                if (row >= M) continue;
                float v = acc[mt][nt][r] + bv;
                if (ACT == ACT_TANH) v = fast_tanh(v);
                else if (ACT == ACT_RELU) v = fmaxf(v, 0.f);
                if (OUT_BF16) ((ushort_t*)Cv)[(size_t)row * N + col] = f2bf(v);
                else ((float*)Cv)[(size_t)row * N + col] = v;
            }
        }
    }
}

// ---------------------------------------------------------------------------
// FUSED 2-layer MLP: out[M][128] = relu(relu(A@W1 + b1) @ W2 + b2)
//   W1t: [512][K1] bf16 pre-transposed; W2t: [128][512] bf16 pre-transposed.
//   GATHER (K1=256): A row m = concat(gsrc[g0[m]], gsrc[g1[m]]), re-gathered
//   per chunk (gsrc is L2-resident). !GATHER (K1=128): A staged resident.
//   Per block: 128 rows, 4 waves (2x2); 4 h-chunks of 128 cols; each chunk
//   GEMM1 -> relu -> Hs (swizzled LDS round-trip) -> GEMM2 accumulate.
//   All LDS tiles use the both-sides XOR swizzle (slot = seg ^ (row&7)).
// ---------------------------------------------------------------------------
template<bool GATHER, int K1, bool OUT_BF16>
__global__ __launch_bounds__(256) void fused_mlp(
    const ushort_t* __restrict__ A, const ushort_t* __restrict__ W1t,
    const float* __restrict__ b1, const ushort_t* __restrict__ W2t,
    const float* __restrict__ b2, void* __restrict__ Cv, int M,
    const int* __restrict__ g0, const int* __restrict__ g1,
    const ushort_t* __restrict__ gsrc)
{
    constexpr int A_ELEMS = GATHER ? (128 * 64) : (128 * 128);
    __shared__ ushort_t As[A_ELEMS];
    __shared__ ushort_t Ws[128 * 64];
    __shared__ ushort_t Hs[128 * 128];   // h chunk, 16-slot swizzled rows

    const int tid = threadIdx.x;
    const int m0 = blockIdx.x * 128;
    const int w = tid >> 6, lane = tid & 63;
    const int wm = w >> 1, wn = w & 1;
    const int lr = lane & 15, lg = lane >> 4;
    const int srow = lane >> 3;            // 8-slot staging: row within 8
    const int sseg = (lane & 7) ^ srow;    // 8-slot staging: source segment

    f32x4 acc2[4][4];
#pragma unroll
    for (int i = 0; i < 4; ++i)
#pragma unroll
        for (int j = 0; j < 4; ++j) acc2[i][j] = (f32x4){0.f, 0.f, 0.f, 0.f};

    if (!GATHER) {
        // stage A resident: [128][128], 16-slot rows (256B), swizzled
        const int arow4 = lane >> 4;       // 0..3
        const int aslot = lane & 15;
#pragma unroll
        for (int rnd = 0; rnd < 8; ++rnd) {
            int row = rnd * 16 + w * 4 + arow4;
            int gm = m0 + row; if (gm >= M) gm = M - 1;
            int seg = aslot ^ (row & 7);
            gload_lds16(A + (size_t)gm * 128 + seg * 8, As + row * 128);
        }
        // barrier happens inside chunk loop before first use
    }

    for (int c = 0; c < 4; ++c) {
        f32x4 acc1[4][4];
#pragma unroll
        for (int i = 0; i < 4; ++i)
#pragma unroll
            for (int j = 0; j < 4; ++j) acc1[i][j] = (f32x4){0.f, 0.f, 0.f, 0.f};

        for (int k0 = 0; k0 < K1; k0 += 64) {
            if (GATHER) {
#pragma unroll
                for (int i = 0; i < 4; ++i) {
                    int ch = w * 4 + i;
                    int row = ch * 8 + srow;
                    int gm = m0 + row; if (gm >= M) gm = M - 1;
                    int src = (k0 >= LATD) ? g1[gm] : g0[gm];
                    gload_lds16(gsrc + (size_t)src * LATD + (k0 & (LATD - 1)) + sseg * 8,
                                As + ch * 512);
                }
            }
#pragma unroll
            for (int i = 0; i < 4; ++i) {
                int ch = w * 4 + i;
                int row = ch * 8 + srow;
                gload_lds16(W1t + (size_t)(c * 128 + row) * K1 + k0 + sseg * 8,
                            Ws + ch * 512);
            }
            __syncthreads();
#pragma unroll
            for (int ks = 0; ks < 2; ++ks) {
                bf16x8 af[4], bf[4];
#pragma unroll
                for (int mt = 0; mt < 4; ++mt) {
                    int row = wm * 64 + mt * 16 + lr;
                    if (GATHER) {
                        int slot = (ks * 4 + lg) ^ (row & 7);
                        af[mt] = *(const bf16x8*)&As[row * 64 + slot * 8];
                    } else {
                        int seg = (k0 >> 3) + ks * 4 + lg;
                        int slot = seg ^ (row & 7);
                        af[mt] = *(const bf16x8*)&As[row * 128 + slot * 8];
                    }
                }
#pragma unroll
                for (int nt = 0; nt < 4; ++nt) {
                    int row = wn * 64 + nt * 16 + lr;
                    int slot = (ks * 4 + lg) ^ (row & 7);
                    bf[nt] = *(const bf16x8*)&Ws[row * 64 + slot * 8];
                }
#pragma unroll
                for (int mt = 0; mt < 4; ++mt)
#pragma unroll
                    for (int nt = 0; nt < 4; ++nt)
                        acc1[mt][nt] = __builtin_amdgcn_mfma_f32_16x16x32_bf16(
                            af[mt], bf[nt], acc1[mt][nt], 0, 0, 0);
            }
            __syncthreads();
        }

        // h = relu(acc1 + b1) -> Hs (row-major [128][128], 16-slot swizzle)
#pragma unroll
        for (int nt = 0; nt < 4; ++nt) {
            int colL = wn * 64 + nt * 16 + lr;          // local h col 0..127
            float bv = b1[c * 128 + colL];
            int cseg = colL >> 3, coff = colL & 7;
#pragma unroll
            for (int mt = 0; mt < 4; ++mt) {
#pragma unroll
                for (int r = 0; r < 4; ++r) {
                    int row = wm * 64 + mt * 16 + lg * 4 + r;
                    float v = fmaxf(acc1[mt][nt][r] + bv, 0.f);
                    int slot = cseg ^ (row & 7);
                    Hs[row * 128 + slot * 8 + coff] = f2bf(v);
                }
            }
        }

        // GEMM2 over this chunk's K-slice (h cols c*128 .. +127)
        for (int k0h = 0; k0h < 128; k0h += 64) {
#pragma unroll
            for (int i = 0; i < 4; ++i) {
                int ch = w * 4 + i;
                int row = ch * 8 + srow;                 // out col 0..127
                gload_lds16(W2t + (size_t)row * HIDD + c * 128 + k0h + sseg * 8,
                            Ws + ch * 512);
            }
            __syncthreads();   // covers Hs writes + Ws stage
#pragma unroll
            for (int ks = 0; ks < 2; ++ks) {
                bf16x8 af[4], bf[4];
#pragma unroll
                for (int mt = 0; mt < 4; ++mt) {
                    int row = wm * 64 + mt * 16 + lr;
                    int seg = (k0h >> 3) + ks * 4 + lg;
                    int slot = seg ^ (row & 7);
                    af[mt] = *(const bf16x8*)&Hs[row * 128 + slot * 8];
                }
#pragma unroll
                for (int nt = 0; nt < 4; ++nt) {
                    int row = wn * 64 + nt * 16 + lr;
                    int slot = (ks * 4 + lg) ^ (row & 7);
                    bf[nt] = *(const bf16x8*)&Ws[row * 64 + slot * 8];
                }
#pragma unroll
                for (int mt = 0; mt < 4; ++mt)
#pragma unroll
                    for (int nt = 0; nt < 4; ++nt)
                        acc2[mt][nt] = __builtin_amdgcn_mfma_f32_16x16x32_bf16(
                            af[mt], bf[nt], acc2[mt][nt], 0, 0, 0);
            }
            __syncthreads();
        }
    }

    // epilogue: out = relu(acc2 + b2)
#pragma unroll
    for (int nt = 0; nt < 4; ++nt) {
        int col = wn * 64 + nt * 16 + lr;
        float bv = b2[col];
#pragma unroll
        for (int mt = 0; mt < 4; ++mt) {
#pragma unroll
            for (int r = 0; r < 4; ++r) {
                int row = m0 + wm * 64 + mt * 16 + lg * 4 + r;
                if (row >= M) continue;
                float v = fmaxf(acc2[mt][nt][r] + bv, 0.f);
                if (OUT_BF16) ((ushort_t*)Cv)[(size_t)row * 128 + col] = f2bf(v);
                else ((float*)Cv)[(size_t)row * 128 + col] = v;
            }
        }
    }
}

// ---------------------------------------------------------------------------
// embeddings = l2norm(h2 @ Wc3 + bc3); THREAD-per-row; h2 bf16.
// ---------------------------------------------------------------------------
__global__ __launch_bounds__(256) void emb_kernel(
    const ushort_t* __restrict__ h2, const float* __restrict__ W,  // [512][12]
    const float* __restrict__ bias, float* __restrict__ out, int M)
{
    __shared__ float Wl[HIDD * EMBD];
    for (int i = threadIdx.x; i < HIDD * EMBD; i += 256) Wl[i] = W[i];
    __syncthreads();

    int m = blockIdx.x * 256 + threadIdx.x;
    if (m >= M) return;
    const ushort_t* row = h2 + (size_t)m * HIDD;

    float acc[EMBD] = {};
#pragma unroll 2
    for (int k0 = 0; k0 < HIDD; k0 += 8) {
        bf16x8 v = *(const bf16x8*)(row + k0);
        float f[8];
#pragma unroll
        for (int u = 0; u < 8; ++u) f[u] = bf2f((ushort_t)v[u]);
#pragma unroll
        for (int u = 0; u < 8; ++u) {
            const float* wr = &Wl[(k0 + u) * EMBD];
#pragma unroll
            for (int j = 0; j < EMBD; ++j) acc[j] += f[u] * wr[j];
        }
    }
    float vv[EMBD];
    float ss = 0.f;
#pragma unroll
    for (int j = 0; j < EMBD; ++j) { vv[j] = acc[j] + bias[j]; ss += vv[j] * vv[j]; }
    float inv = 1.f / fmaxf(sqrtf(ss), 1e-12f);
#pragma unroll
    for (int j = 0; j < EMBD; ++j) out[(size_t)m * EMBD + j] = vv[j] * inv;
}

// ---------------------------------------------------------------------------
__global__ void cluster_accum(const float* __restrict__ emb,
                              const int* __restrict__ clusters,
                              float* __restrict__ csums, float* __restrict__ ccnt)
{
    int n = blockIdx.x * 256 + threadIdx.x;
    if (n >= NN) return;
    int c = clusters[n];
    const float4* row = (const float4*)(emb + (size_t)n * EMBD);
    float4 r0 = row[0], r1 = row[1], r2 = row[2];
    float* dst = &csums[(size_t)c * EMBD];
    atomicAdd(&dst[0], r0.x);  atomicAdd(&dst[1], r0.y);
    atomicAdd(&dst[2], r0.z);  atomicAdd(&dst[3], r0.w);
    atomicAdd(&dst[4], r1.x);  atomicAdd(&dst[5], r1.y);
    atomicAdd(&dst[6], r1.z);  atomicAdd(&dst[7], r1.w);
    atomicAdd(&dst[8], r2.x);  atomicAdd(&dst[9], r2.y);
    atomicAdd(&dst[10], r2.z); atomicAdd(&dst[11], r2.w);
    atomicAdd(&ccnt[c], 1.f);
}

__global__ void means_kernel(const float* __restrict__ csums,
                             const float* __restrict__ ccnt,
                             float* __restrict__ means)
{
    int c = blockIdx.x * 256 + threadIdx.x;
    if (c >= NC) return;
    float cv = fmaxf(ccnt[c], 1.f);
    float v[EMBD];
    float ss = 0.f;
#pragma unroll
    for (int j = 0; j < EMBD; ++j) {
        v[j] = csums[(size_t)c * EMBD + j] / cv;
        ss += v[j] * v[j];
    }
    float inv = 1.f / fmaxf(sqrtf(ss), 1e-12f);
#pragma unroll
    for (int j = 0; j < EMBD; ++j) means[(size_t)c * EMBD + j] = v[j] * inv;
}

// ---------------------------------------------------------------------------
__device__ __forceinline__ void block_stats2(float x, float x2, float* s_sum, float* s_sumsq)
{
#pragma unroll
    for (int s = 32; s >= 1; s >>= 1) {
        x += __shfl_xor(x, s, 64);
        x2 += __shfl_xor(x2, s, 64);
    }
    __shared__ float w0[4], w1[4];
    int lane = threadIdx.x & 63, w = threadIdx.x >> 6;
    if (lane == 0) { w0[w] = x; w1[w] = x2; }
    __syncthreads();
    if (threadIdx.x == 0) {
        float a = 0.f, b = 0.f;
        for (int i = 0; i < 4; ++i) { a += w0[i]; b += w1[i]; }
        atomicAdd(s_sum, a);
        atomicAdd(s_sumsq, b);
    }
}

// ---------------------------------------------------------------------------
__global__ __launch_bounds__(256) void sg_lik_kernel(
    const float* __restrict__ means, const int* __restrict__ sg0,
    const int* __restrict__ sg1, float* __restrict__ sg_lik, float* __restrict__ stats)
{
    int base = (blockIdx.x * 256 + threadIdx.x) * 4;
    float xs = 0.f, xs2 = 0.f;
    if (base < NES) {
        int4 a4 = *(const int4*)(sg0 + base);
        int4 b4 = *(const int4*)(sg1 + base);
        int ai[4] = {a4.x, a4.y, a4.z, a4.w};
        int bi[4] = {b4.x, b4.y, b4.z, b4.w};
        float4 av[4][3], bv[4][3];
#pragma unroll
        for (int i = 0; i < 4; ++i) {
            const float4* ap = (const float4*)(means + (size_t)ai[i] * EMBD);
            const float4* bp = (const float4*)(means + (size_t)bi[i] * EMBD);
            av[i][0] = ap[0]; av[i][1] = ap[1]; av[i][2] = ap[2];
            bv[i][0] = bp[0]; bv[i][1] = bp[1]; bv[i][2] = bp[2];
        }
        float4 o;
        float* op = (float*)&o;
#pragma unroll
        for (int i = 0; i < 4; ++i) {
            float s = av[i][0].x * bv[i][0].x + av[i][0].y * bv[i][0].y
                    + av[i][0].z * bv[i][0].z + av[i][0].w * bv[i][0].w
                    + av[i][1].x * bv[i][1].x + av[i][1].y * bv[i][1].y
                    + av[i][1].z * bv[i][1].z + av[i][1].w * bv[i][1].w
                    + av[i][2].x * bv[i][2].x + av[i][2].y * bv[i][2].y
                    + av[i][2].z * bv[i][2].z + av[i][2].w * bv[i][2].w;
            op[i] = s;
            xs += s; xs2 += s * s;
        }
        *(float4*)(sg_lik + base) = o;
    }
    block_stats2(xs, xs2, &stats[0], &stats[1]);
}

__global__ __launch_bounds__(256) void sgw_kernel(
    const float* __restrict__ sg_lik, const float* __restrict__ stats,
    const float* __restrict__ gamma, const float* __restrict__ beta,
    float* __restrict__ out)
{
    int base = (blockIdx.x * 256 + threadIdx.x) * 4;
    if (base >= NES) return;
    float m = stats[0] / (float)NES;
    float var = stats[1] / (float)NES - m * m;
    float rs = rsqrtf(var + 1e-5f) * gamma[0];
    float4 v = *(const float4*)(sg_lik + base);
    float4 o;
    o.x = 1.f / (1.f + __expf(-((v.x - m) * rs + beta[0])));
    o.y = 1.f / (1.f + __expf(-((v.y - m) * rs + beta[0])));
    o.z = 1.f / (1.f + __expf(-((v.z - m) * rs + beta[0])));
    o.w = 1.f / (1.f + __expf(-((v.w - m) * rs + beta[0])));
    *(float4*)(out + base) = o;
}

// ---------------------------------------------------------------------------
__global__ __launch_bounds__(256) void bg_lik_kernel(
    const float* __restrict__ emb, const float* __restrict__ means,
    const int* __restrict__ bg_src, const int* __restrict__ bg_dst,
    float* __restrict__ bg_lik, float* __restrict__ stats, int* __restrict__ cnt)
{
    int base = (blockIdx.x * 256 + threadIdx.x) * 4;
    float xs = 0.f, xs2 = 0.f;
    if (base < NEB) {
        int4 s4 = *(const int4*)(bg_src + base);
        int4 d4 = *(const int4*)(bg_dst + base);
        int si[4] = {s4.x, s4.y, s4.z, s4.w};
        int di[4] = {d4.x, d4.y, d4.z, d4.w};
        float4 av[4][3], bv[4][3];
#pragma unroll
        for (int i = 0; i < 4; ++i) {
            const float4* ap = (const float4*)(emb + (size_t)si[i] * EMBD);
            const float4* bp = (const float4*)(means + (size_t)di[i] * EMBD);
            av[i][0] = ap[0]; av[i][1] = ap[1]; av[i][2] = ap[2];
            bv[i][0] = bp[0]; bv[i][1] = bp[1]; bv[i][2] = bp[2];
        }
#pragma unroll
        for (int i = 0; i < 4; ++i) atomicAdd(&cnt[di[i]], 1);
        float4 o;
        float* op = (float*)&o;
#pragma unroll
        for (int i = 0; i < 4; ++i) {
            float s = av[i][0].x * bv[i][0].x + av[i][0].y * bv[i][0].y
                    + av[i][0].z * bv[i][0].z + av[i][0].w * bv[i][0].w
                    + av[i][1].x * bv[i][1].x + av[i][1].y * bv[i][1].y
                    + av[i][1].z * bv[i][1].z + av[i][1].w * bv[i][1].w
                    + av[i][2].x * bv[i][2].x + av[i][2].y * bv[i][2].y
                    + av[i][2].z * bv[i][2].z + av[i][2].w * bv[i][2].w;
            op[i] = s;
            xs += s; xs2 += s * s;
        }
        *(float4*)(bg_lik + base) = o;
    }
    block_stats2(xs, xs2, &stats[2], &stats[3]);
}

__global__ __launch_bounds__(256) void bw_kernel(
    const float* __restrict__ bg_lik, const float* __restrict__ stats,
    const float* __restrict__ gamma, const float* __restrict__ beta,
    const int* __restrict__ bg_src, float* __restrict__ bw, float* __restrict__ denom)
{
    int base = (blockIdx.x * 256 + threadIdx.x) * 4;
    if (base >= NEB) return;
    float m = stats[2] / (float)NEB;
    float var = stats[3] / (float)NEB - m * m;
    float rs = rsqrtf(var + 1e-5f) * gamma[0];
    int4 s4 = *(const int4*)(bg_src + base);
    int si[4] = {s4.x, s4.y, s4.z, s4.w};
    float4 v = *(const float4*)(bg_lik + base);
    float vi[4] = {v.x, v.y, v.z, v.w};
    float4 o;
    float* op = (float*)&o;
#pragma unroll
    for (int i = 0; i < 4; ++i) {
        float w = __expf((vi[i] - m) * rs + beta[0]);
        op[i] = w;
        atomicAdd(&denom[si[i]], w);
    }
    *(float4*)(bw + base) = o;
}

__global__ __launch_bounds__(256) void bw_norm_kernel(
    float* __restrict__ bw, const float* __restrict__ denom,
    const int* __restrict__ bg_src, float* __restrict__ out)
{
    int base = (blockIdx.x * 256 + threadIdx.x) * 4;
    if (base >= NEB) return;
    int4 s4 = *(const int4*)(bg_src + base);
    int si[4] = {s4.x, s4.y, s4.z, s4.w};
    float dv[4];
#pragma unroll
    for (int i = 0; i < 4; ++i) dv[i] = denom[si[i]];
    float4 v = *(const float4*)(bw + base);
    float4 o;
    o.x = v.x / (1e-12f + dv[0]);
    o.y = v.y / (1e-12f + dv[1]);
    o.z = v.z / (1e-12f + dv[2]);
    o.w = v.w / (1e-12f + dv[3]);
    *(float4*)(bw + base) = o;
    *(float4*)(out + base) = o;
}

// ---------------------------------------------------------------------------
__global__ __launch_bounds__(1024) void scan_kernel(
    const int* __restrict__ cnt, int* __restrict__ offs, int C)
{
    __shared__ int wsum[16];
    __shared__ int carry_s, ctot_s;
    const int tid = threadIdx.x;
    const int lane = tid & 63, w = tid >> 6;
    if (tid == 0) carry_s = 0;
    __syncthreads();
    for (int base = 0; base < C; base += 1024) {
        int i = base + tid;
        int v = (i < C) ? cnt[i] : 0;
        int x = v;
#pragma unroll
        for (int s = 1; s < 64; s <<= 1) {
            int y = __shfl_up(x, s, 64);
            if (lane >= s) x += y;
        }
        if (lane == 63) wsum[w] = x;
        __syncthreads();
        if (tid == 0) {
            int s = 0;
            for (int k = 0; k < 16; ++k) { int t = wsum[k]; wsum[k] = s; s += t; }
            ctot_s = s;
        }
        __syncthreads();
        int excl = carry_s + wsum[w] + (x - v);
        if (i < C) offs[i] = excl;
        __syncthreads();
        if (tid == 0) carry_s += ctot_s;
        __syncthreads();
    }
    if (tid == 0) offs[C] = carry_s;
}

__global__ void scatter_kernel(const int* __restrict__ bg_dst,
                               const int* __restrict__ offs,
                               int* __restrict__ fill, int* __restrict__ eids)
{
    int base = (blockIdx.x * 256 + threadIdx.x) * 4;
    if (base >= NEB) return;
    int4 d4 = *(const int4*)(bg_dst + base);
    int di[4] = {d4.x, d4.y, d4.z, d4.w};
#pragma unroll
    for (int i = 0; i < 4; ++i) {
        int p = atomicAdd(&fill[di[i]], 1);
        eids[offs[di[i]] + p] = base + i;
    }
}

// ---------------------------------------------------------------------------
// supernodes: lane-packed gather (16 lanes x 16B = one 256B row per instr)
// ---------------------------------------------------------------------------
__global__ __launch_bounds__(256) void supernodes_kernel(
    const ushort_t* __restrict__ nmsg, const float* __restrict__ bw,
    const int* __restrict__ bg_src, const int* __restrict__ eids,
    const int* __restrict__ offs, float* __restrict__ sn)
{
    __shared__ float red[4][LATD];
    const int c = blockIdx.x;
    const int tid = threadIdx.x;
    const int wv = tid >> 6, lane = tid & 63;
    const int er = lane >> 4;
    const int cg = lane & 15;
    const int beg = offs[c], end = offs[c + 1];

    float acc[8] = {};
    for (int p = beg + wv * 4 + er; p < end; p += 16) {
        int e = eids[p];
        int s = bg_src[e];
        float w = bw[e];
        bf16x8 v = *(const bf16x8*)(nmsg + (size_t)s * LATD + cg * 8);
#pragma unroll
        for (int j = 0; j < 8; ++j) acc[j] += w * bf2f((ushort_t)v[j]);
    }
#pragma unroll
    for (int j = 0; j < 8; ++j) {
        acc[j] += __shfl_xor(acc[j], 16, 64);
        acc[j] += __shfl_xor(acc[j], 32, 64);
    }
    if (lane < 16) {
        *(float4*)&red[wv][cg * 8]     = (float4){acc[0], acc[1], acc[2], acc[3]};
        *(float4*)&red[wv][cg * 8 + 4] = (float4){acc[4], acc[5], acc[6], acc[7]};
    }
    __syncthreads();
    if (tid < LATD) {
        float s = red[0][tid] + red[1][tid] + red[2][tid] + red[3][tid];
        sn[(size_t)c * LATD + tid] = s;
    }
}

// ---------------------------------------------------------------------------
extern "C" void kernel_launch(void* const* d_in, const int* in_sizes, int n_in,
                              void* d_out, int out_size, void* d_ws, size_t ws_size,
                              hipStream_t stream)
{
    const float* emb_nodes = (const float*)d_in[0];
    const float* enc_nodes = (const float*)d_in[1];
    const float* Wc1 = (const float*)d_in[2];  const float* bc1 = (const float*)d_in[3];
    const float* Wc2 = (const float*)d_in[4];  const float* bc2 = (const float*)d_in[5];
    const float* Wc3 = (const float*)d_in[6];  const float* bc3 = (const float*)d_in[7];
    const float* Wn1 = (const float*)d_in[8];  const float* cn1 = (const float*)d_in[9];
    const float* Wn2 = (const float*)d_in[10]; const float* cn2 = (const float*)d_in[11];
    const float* We1 = (const float*)d_in[12]; const float* ce1 = (const float*)d_in[13];
    const float* We2 = (const float*)d_in[14]; const float* ce2 = (const float*)d_in[15];
    const float* sg_gamma = (const float*)d_in[16]; const float* sg_beta = (const float*)d_in[17];
    const float* bg_gamma = (const float*)d_in[18]; const float* bg_beta = (const float*)d_in[19];
    const int* clusters = (const int*)d_in[20];
    const int* sg0 = (const int*)d_in[21];
    const int* sg1 = sg0 + NES;
    const int* bg_src = (const int*)d_in[22];
    const int* bg_dst = (const int*)d_in[23];

    // output layout (flat, return order)
    float* out_emb = (float*)d_out;                       // NN*EMBD
    float* out_sn  = out_emb + (size_t)NN * EMBD;         // NC*LATD
    float* out_se  = out_sn + (size_t)NC * LATD;          // NES*LATD
    float* out_bw  = out_se + (size_t)NES * LATD;         // NEB
    float* out_sew = out_bw + (size_t)NEB;                // NES

    // ---------------- workspace layout (byte cursor, 64B-aligned) ----------
    uintptr_t cur = (uintptr_t)d_ws;
    uintptr_t wend = cur + ws_size;
    auto alloc = [&](size_t bytes) -> void* {
        cur = (cur + 63) & ~(uintptr_t)63;
        void* p = (void*)cur;
        cur += bytes;
        return p;
    };

    // zeroed region (contiguous)
    float* zbase = (float*)alloc(((size_t)NC * EMBD + NC + NN + 8 + NC + NC) * 4);
    float* csums = zbase;
    float* ccnt  = csums + (size_t)NC * EMBD;
    float* denom = ccnt + NC;
    float* stats = denom + NN;
    int*   cnt   = (int*)(stats + 8);
    int*   fill  = cnt + NC;
    size_t zero_bytes = ((size_t)NC * EMBD + NC + NN + 8 + NC + NC) * 4;

    float* means  = (float*)alloc((size_t)NC * EMBD * 4);
    float* sg_lik = (float*)alloc((size_t)NES * 4);
    float* bg_lik = (float*)alloc((size_t)NEB * 4);
    float* bwv    = (float*)alloc((size_t)NEB * 4);
    int*   offs   = (int*)alloc((size_t)(NC + 1) * 4);
    int*   eids   = (int*)alloc((size_t)NEB * 4);

    ushort_t* xemb   = (ushort_t*)alloc((size_t)NN * LATD * 2);
    ushort_t* xenc   = (ushort_t*)alloc((size_t)NN * LATD * 2);
    ushort_t* nmsgb  = (ushort_t*)alloc((size_t)NN * LATD * 2);
    ushort_t* sn_bf  = (ushort_t*)alloc((size_t)NC * LATD * 2);
    ushort_t* Wc1t = (ushort_t*)alloc((size_t)LATD * HIDD * 2);
    ushort_t* Wc2t = (ushort_t*)alloc((size_t)HIDD * HIDD * 2);
    ushort_t* Wn1t = (ushort_t*)alloc((size_t)LATD * HIDD * 2);
    ushort_t* Wn2t = (ushort_t*)alloc((size_t)HIDD * LATD * 2);
    ushort_t* We1t = (ushort_t*)alloc((size_t)2 * LATD * HIDD * 2);
    ushort_t* We2t = (ushort_t*)alloc((size_t)HIDD * LATD * 2);

    cur = (cur + 63) & ~(uintptr_t)63;
    size_t rem_bytes = (wend > cur) ? (size_t)(wend - cur) : 0;
    size_t chunk_sz = (rem_bytes / (2 * (size_t)HIDD * 2)) & ~(size_t)127;
    if (chunk_sz > 51200) chunk_sz = 51200;
    if (chunk_sz < 256) return;  // fail soft
    const int CH = (int)chunk_sz;
    ushort_t* bufA = (ushort_t*)cur;
    ushort_t* bufB = bufA + (size_t)CH * HIDD;

    hipMemsetAsync(zbase, 0, zero_bytes, stream);

    dim3 blk(256);

    // ---- prep: input/weight conversions ----
    conv_f2b_kernel<<<2048, blk, 0, stream>>>(emb_nodes, xemb, (long)NN * LATD);
    conv_f2b_kernel<<<2048, blk, 0, stream>>>(enc_nodes, xenc, (long)NN * LATD);
    transpose_conv_kernel<<<(LATD * HIDD + 255) / 256, blk, 0, stream>>>(Wc1, Wc1t, LATD, HIDD);
    transpose_conv_kernel<<<(HIDD * HIDD + 255) / 256, blk, 0, stream>>>(Wc2, Wc2t, HIDD, HIDD);
    transpose_conv_kernel<<<(LATD * HIDD + 255) / 256, blk, 0, stream>>>(Wn1, Wn1t, LATD, HIDD);
    transpose_conv_kernel<<<(HIDD * LATD + 255) / 256, blk, 0, stream>>>(Wn2, Wn2t, HIDD, LATD);
    transpose_conv_kernel<<<(2 * LATD * HIDD + 255) / 256, blk, 0, stream>>>(We1, We1t, 2 * LATD, HIDD);
    transpose_conv_kernel<<<(HIDD * LATD + 255) / 256, blk, 0, stream>>>(We2, We2t, HIDD, LATD);

    // ---- fused node chain, chunked: xemb->h1->h2->embeddings ----
    for (int m0 = 0; m0 < NN; m0 += CH) {
        int cm = (NN - m0 < CH) ? (NN - m0) : CH;
        gemm_mfma<ACT_TANH, true><<<dim3(HIDD / 128, (cm + 127) / 128), blk, 0, stream>>>(
            xemb + (size_t)m0 * LATD, Wc1t, bc1, bufA, cm, HIDD, LATD);
        gemm_mfma<ACT_TANH, true><<<dim3(HIDD / 128, (cm + 127) / 128), blk, 0, stream>>>(
            bufA, Wc2t, bc2, bufB, cm, HIDD, HIDD);
        emb_kernel<<<(cm + 255) / 256, blk, 0, stream>>>(
            bufB, Wc3, bc3, out_emb + (size_t)m0 * EMBD, cm);
    }

    // ---- cluster means ----
    cluster_accum<<<(NN + 255) / 256, blk, 0, stream>>>(out_emb, clusters, csums, ccnt);
    means_kernel<<<(NC + 255) / 256, blk, 0, stream>>>(csums, ccnt, means);

    // ---- super edge weights (4 edges/thread) ----
    sg_lik_kernel<<<(NES / 4 + 255) / 256, blk, 0, stream>>>(means, sg0, sg1, sg_lik, stats);
    sgw_kernel<<<(NES / 4 + 255) / 256, blk, 0, stream>>>(sg_lik, stats, sg_gamma, sg_beta, out_sew);

    // ---- bipartite edge weights (hist fused; 4 edges/thread) ----
    bg_lik_kernel<<<(NEB / 4 + 255) / 256, blk, 0, stream>>>(out_emb, means, bg_src, bg_dst, bg_lik, stats, cnt);
    bw_kernel<<<(NEB / 4 + 255) / 256, blk, 0, stream>>>(bg_lik, stats, bg_gamma, bg_beta, bg_src, bwv, denom);
    bw_norm_kernel<<<(NEB / 4 + 255) / 256, blk, 0, stream>>>(bwv, denom, bg_src, out_bw);

    // ---- counting sort of edges by destination cluster ----
    scan_kernel<<<1, 1024, 0, stream>>>(cnt, offs, NC);
    scatter_kernel<<<(NEB / 4 + 255) / 256, blk, 0, stream>>>(bg_dst, offs, fill, eids);

    // ---- node messages: FUSED relu(relu(xenc@Wn1)@Wn2) -> nmsgb (bf16) ----
    fused_mlp<false, LATD, true><<<(NN + 127) / 128, blk, 0, stream>>>(
        xenc, Wn1t, cn1, Wn2t, cn2, nmsgb, NN, nullptr, nullptr, nullptr);

    // ---- supernodes (sorted edge lists, no atomics; lane-packed gather) ----
    supernodes_kernel<<<NC, blk, 0, stream>>>(nmsgb, bwv, bg_src, eids, offs, out_sn);
    conv_f2b_kernel<<<512, blk, 0, stream>>>(out_sn, sn_bf, (long)NC * LATD);

    // ---- superedges: FUSED relu(relu(gather@We1)@We2) -> out_se (fp32) ----
    fused_mlp<true, 2 * LATD, false><<<(NES + 127) / 128, blk, 0, stream>>>(
        nullptr, We1t, ce1, We2t, ce2, out_se, NES, sg0, sg1, sn_bf);
}

// Round 10
// 908.236 us; speedup vs baseline: 1.2266x; 1.0234x over previous
//
#include <hip/hip_runtime.h>
#include <cstdint>
#include <cstddef>

// Problem constants (SuperGraphConstruction)
#define NN 100000      // nodes
#define NC 20000       // clusters
#define LATD 128
#define HIDD 512
#define EMBD 12
#define NES 160000     // super edges
#define NEB 800000     // bipartite edges

enum { ACT_NONE = 0, ACT_TANH = 1, ACT_RELU = 2 };

typedef __attribute__((ext_vector_type(8))) short bf16x8;
typedef __attribute__((ext_vector_type(4))) float f32x4;
typedef unsigned short ushort_t;

__device__ __forceinline__ float fast_tanh(float x) {
    return 1.f - 2.f / (__expf(2.f * x) + 1.f);
}
__device__ __forceinline__ ushort_t f2bf(float f) {
    union { float f; unsigned u; } x; x.f = f;
    unsigned r = x.u + 0x7FFFu + ((x.u >> 16) & 1u);  // RNE
    return (ushort_t)(r >> 16);
}
__device__ __forceinline__ float bf2f(ushort_t h) {
    union { unsigned u; float f; } x; x.u = ((unsigned)h) << 16;
    return x.f;
}

typedef __attribute__((address_space(1))) void gvoid_t;
typedef __attribute__((address_space(3))) void svoid_t;
__device__ __forceinline__ void gload_lds16(const void* g, void* l) {
    __builtin_amdgcn_global_load_lds((gvoid_t*)g, (svoid_t*)l, 16, 0, 0);
}

// ---------------------------------------------------------------------------
__global__ __launch_bounds__(256) void conv_f2b_kernel(
    const float* __restrict__ in, ushort_t* __restrict__ out, long n)
{
    long i = ((long)blockIdx.x * 256 + threadIdx.x) * 8;
    long stride = (long)gridDim.x * 256 * 8;
    for (; i + 7 < n; i += stride) {
        float4 a = *(const float4*)(in + i);
        float4 b = *(const float4*)(in + i + 4);
        ushort_t o[8] = { f2bf(a.x), f2bf(a.y), f2bf(a.z), f2bf(a.w),
                          f2bf(b.x), f2bf(b.y), f2bf(b.z), f2bf(b.w) };
        *(int4*)(out + i) = *(int4*)o;
    }
}

// W [K][N] fp32 -> Wt [N][K] bf16
__global__ __launch_bounds__(256) void transpose_conv_kernel(
    const float* __restrict__ W, ushort_t* __restrict__ Wt, int K, int N)
{
    int i = blockIdx.x * 256 + threadIdx.x;
    if (i >= K * N) return;
    int n = i / K, k = i % K;
    Wt[i] = f2bf(W[(size_t)k * N + n]);
}

// ---------------------------------------------------------------------------
// bf16 MFMA GEMM (m97 + T2 swizzle)
// ---------------------------------------------------------------------------
template<int ACT, bool OUT_BF16>
__global__ __launch_bounds__(256) void gemm_mfma(
    const ushort_t* __restrict__ A, const ushort_t* __restrict__ Bt,
    const float* __restrict__ bias, void* __restrict__ Cv,
    int M, int N, int K)
{
    __shared__ ushort_t As[128 * 64];
    __shared__ ushort_t Bs[128 * 64];

    const int tid = threadIdx.x;
    const int m0 = blockIdx.y * 128, n0 = blockIdx.x * 128;
    const int w = tid >> 6, lane = tid & 63;
    const int wm = w >> 1, wn = w & 1;
    const int lr = lane & 15, lg = lane >> 4;
    const int srow = lane >> 3;
    const int sseg = (lane & 7) ^ srow;

    f32x4 acc[4][4];
#pragma unroll
    for (int i = 0; i < 4; ++i)
#pragma unroll
        for (int j = 0; j < 4; ++j) acc[i][j] = (f32x4){0.f, 0.f, 0.f, 0.f};

    for (int k0 = 0; k0 < K; k0 += 64) {
#pragma unroll
        for (int i = 0; i < 4; ++i) {
            int c = w * 4 + i;
            int row = c * 8 + srow;
            int gm = m0 + row; if (gm >= M) gm = M - 1;
            gload_lds16(A + (size_t)gm * K + k0 + sseg * 8, As + c * 512);
            gload_lds16(Bt + (size_t)(n0 + row) * K + k0 + sseg * 8, Bs + c * 512);
        }
        __syncthreads();
#pragma unroll
        for (int ks = 0; ks < 2; ++ks) {
            bf16x8 af[4], bf[4];
#pragma unroll
            for (int mt = 0; mt < 4; ++mt) {
                int row = wm * 64 + mt * 16 + lr;
                int slot = (ks * 4 + lg) ^ (row & 7);
                af[mt] = *(const bf16x8*)&As[row * 64 + slot * 8];
            }
#pragma unroll
            for (int nt = 0; nt < 4; ++nt) {
                int row = wn * 64 + nt * 16 + lr;
                int slot = (ks * 4 + lg) ^ (row & 7);
                bf[nt] = *(const bf16x8*)&Bs[row * 64 + slot * 8];
            }
#pragma unroll
            for (int mt = 0; mt < 4; ++mt)
#pragma unroll
                for (int nt = 0; nt < 4; ++nt)
                    acc[mt][nt] = __builtin_amdgcn_mfma_f32_16x16x32_bf16(
                        af[mt], bf[nt], acc[mt][nt], 0, 0, 0);
        }
        __syncthreads();
    }

#pragma unroll
    for (int nt = 0; nt < 4; ++nt) {
        int col = n0 + wn * 64 + nt * 16 + lr;
        float bv = bias[col];
#pragma unroll
        for (int mt = 0; mt < 4; ++mt) {
#pragma unroll
            for (int r = 0; r < 4; ++r) {
                int row = m0 + wm * 64 + mt * 16 + lg * 4 + r;
                if (row >= M) continue;
                float v = acc[mt][nt][r] + bv;
                if (ACT == ACT_TANH) v = fast_tanh(v);
                else if (ACT == ACT_RELU) v = fmaxf(v, 0.f);
                if (OUT_BF16) ((ushort_t*)Cv)[(size_t)row * N + col] = f2bf(v);
                else ((float*)Cv)[(size_t)row * N + col] = v;
            }
        }
    }
}

// ---------------------------------------------------------------------------
// FUSED 2-layer MLP (node messages): out = relu(relu(A@W1+b1)@W2+b2)
// A staged resident [128][128]; 4 h-chunks via swizzled Hs round-trip.
// ---------------------------------------------------------------------------
template<bool OUT_BF16>
__global__ __launch_bounds__(256) void fused_mlp(
    const ushort_t* __restrict__ A, const ushort_t* __restrict__ W1t,
    const float* __restrict__ b1, const ushort_t* __restrict__ W2t,
    const float* __restrict__ b2, void* __restrict__ Cv, int M)
{
    __shared__ ushort_t As[128 * 128];
    __shared__ ushort_t Ws[128 * 64];
    __shared__ ushort_t Hs[128 * 128];

    const int tid = threadIdx.x;
    const int m0 = blockIdx.x * 128;
    const int w = tid >> 6, lane = tid & 63;
    const int wm = w >> 1, wn = w & 1;
    const int lr = lane & 15, lg = lane >> 4;
    const int srow = lane >> 3;
    const int sseg = (lane & 7) ^ srow;

    f32x4 acc2[4][4];
#pragma unroll
    for (int i = 0; i < 4; ++i)
#pragma unroll
        for (int j = 0; j < 4; ++j) acc2[i][j] = (f32x4){0.f, 0.f, 0.f, 0.f};

    {   // stage A resident: [128][128], 16-slot swizzled rows
        const int arow4 = lane >> 4;
        const int aslot = lane & 15;
#pragma unroll
        for (int rnd = 0; rnd < 8; ++rnd) {
            int row = rnd * 16 + w * 4 + arow4;
            int gm = m0 + row; if (gm >= M) gm = M - 1;
            int seg = aslot ^ (row & 7);
            gload_lds16(A + (size_t)gm * 128 + seg * 8, As + row * 128);
        }
    }

    for (int c = 0; c < 4; ++c) {
        f32x4 acc1[4][4];
#pragma unroll
        for (int i = 0; i < 4; ++i)
#pragma unroll
            for (int j = 0; j < 4; ++j) acc1[i][j] = (f32x4){0.f, 0.f, 0.f, 0.f};

        for (int k0 = 0; k0 < 128; k0 += 64) {
#pragma unroll
            for (int i = 0; i < 4; ++i) {
                int ch = w * 4 + i;
                int row = ch * 8 + srow;
                gload_lds16(W1t + (size_t)(c * 128 + row) * 128 + k0 + sseg * 8,
                            Ws + ch * 512);
            }
            __syncthreads();
#pragma unroll
            for (int ks = 0; ks < 2; ++ks) {
                bf16x8 af[4], bf[4];
#pragma unroll
                for (int mt = 0; mt < 4; ++mt) {
                    int row = wm * 64 + mt * 16 + lr;
                    int seg = (k0 >> 3) + ks * 4 + lg;
                    int slot = seg ^ (row & 7);
                    af[mt] = *(const bf16x8*)&As[row * 128 + slot * 8];
                }
#pragma unroll
                for (int nt = 0; nt < 4; ++nt) {
                    int row = wn * 64 + nt * 16 + lr;
                    int slot = (ks * 4 + lg) ^ (row & 7);
                    bf[nt] = *(const bf16x8*)&Ws[row * 64 + slot * 8];
                }
#pragma unroll
                for (int mt = 0; mt < 4; ++mt)
#pragma unroll
                    for (int nt = 0; nt < 4; ++nt)
                        acc1[mt][nt] = __builtin_amdgcn_mfma_f32_16x16x32_bf16(
                            af[mt], bf[nt], acc1[mt][nt], 0, 0, 0);
            }
            __syncthreads();
        }

        // h = relu(acc1 + b1) -> Hs
#pragma unroll
        for (int nt = 0; nt < 4; ++nt) {
            int colL = wn * 64 + nt * 16 + lr;
            float bv = b1[c * 128 + colL];
            int cseg = colL >> 3, coff = colL & 7;
#pragma unroll
            for (int mt = 0; mt < 4; ++mt) {
#pragma unroll
                for (int r = 0; r < 4; ++r) {
                    int row = wm * 64 + mt * 16 + lg * 4 + r;
                    float v = fmaxf(acc1[mt][nt][r] + bv, 0.f);
                    int slot = cseg ^ (row & 7);
                    Hs[row * 128 + slot * 8 + coff] = f2bf(v);
                }
            }
        }

        for (int k0h = 0; k0h < 128; k0h += 64) {
#pragma unroll
            for (int i = 0; i < 4; ++i) {
                int ch = w * 4 + i;
                int row = ch * 8 + srow;
                gload_lds16(W2t + (size_t)row * HIDD + c * 128 + k0h + sseg * 8,
                            Ws + ch * 512);
            }
            __syncthreads();
#pragma unroll
            for (int ks = 0; ks < 2; ++ks) {
                bf16x8 af[4], bf[4];
#pragma unroll
                for (int mt = 0; mt < 4; ++mt) {
                    int row = wm * 64 + mt * 16 + lr;
                    int seg = (k0h >> 3) + ks * 4 + lg;
                    int slot = seg ^ (row & 7);
                    af[mt] = *(const bf16x8*)&Hs[row * 128 + slot * 8];
                }
#pragma unroll
                for (int nt = 0; nt < 4; ++nt) {
                    int row = wn * 64 + nt * 16 + lr;
                    int slot = (ks * 4 + lg) ^ (row & 7);
                    bf[nt] = *(const bf16x8*)&Ws[row * 64 + slot * 8];
                }
#pragma unroll
                for (int mt = 0; mt < 4; ++mt)
#pragma unroll
                    for (int nt = 0; nt < 4; ++nt)
                        acc2[mt][nt] = __builtin_amdgcn_mfma_f32_16x16x32_bf16(
                            af[mt], bf[nt], acc2[mt][nt], 0, 0, 0);
            }
            __syncthreads();
        }
    }

#pragma unroll
    for (int nt = 0; nt < 4; ++nt) {
        int col = wn * 64 + nt * 16 + lr;
        float bv = b2[col];
#pragma unroll
        for (int mt = 0; mt < 4; ++mt) {
#pragma unroll
            for (int r = 0; r < 4; ++r) {
                int row = m0 + wm * 64 + mt * 16 + lg * 4 + r;
                if (row >= M) continue;
                float v = fmaxf(acc2[mt][nt][r] + bv, 0.f);
                if (OUT_BF16) ((ushort_t*)Cv)[(size_t)row * 128 + col] = f2bf(v);
                else ((float*)Cv)[(size_t)row * 128 + col] = v;
            }
        }
    }
}

// ---------------------------------------------------------------------------
// FUSED superedge: out = relu( relu(P0[g0]+P1[g1]+b1) @ W2 + b2 )
//   P0,P1: [NC][512] bf16 (premultiplied sn@We1_top / sn@We1_bot).
//   Per block 128 edges; 4 h-chunks of 128 cols: lane-packed gather-add-relu
//   into swizzled Hs, then GEMM2 accumulate. LDS 49KB -> 3 blocks/CU.
// ---------------------------------------------------------------------------
__global__ __launch_bounds__(256) void fused_edge(
    const ushort_t* __restrict__ P0, const ushort_t* __restrict__ P1,
    const float* __restrict__ b1, const ushort_t* __restrict__ W2t,
    const float* __restrict__ b2, float* __restrict__ Cv, int M,
    const int* __restrict__ g0, const int* __restrict__ g1)
{
    __shared__ ushort_t Hs[128 * 128];
    __shared__ ushort_t Ws[128 * 64];
    __shared__ int i0s[128], i1s[128];

    const int tid = threadIdx.x;
    const int m0 = blockIdx.x * 128;
    const int w = tid >> 6, lane = tid & 63;
    const int wm = w >> 1, wn = w & 1;
    const int lr = lane & 15, lg = lane >> 4;
    const int srow = lane >> 3;
    const int sseg = (lane & 7) ^ srow;
    const int er = lane >> 4;        // edge slot 0..3 within wave
    const int cg = lane & 15;        // 16B segment within 256B chunk row

    if (tid < 128) {
        int gm = m0 + tid; if (gm >= M) gm = M - 1;
        i0s[tid] = g0[gm];
        i1s[tid] = g1[gm];
    }
    __syncthreads();

    f32x4 acc2[4][4];
#pragma unroll
    for (int i = 0; i < 4; ++i)
#pragma unroll
        for (int j = 0; j < 4; ++j) acc2[i][j] = (f32x4){0.f, 0.f, 0.f, 0.f};

    for (int c = 0; c < 4; ++c) {
        // per-lane bias slice (fixed cg across passes)
        float bch[8];
#pragma unroll
        for (int j = 0; j < 8; ++j) bch[j] = b1[c * 128 + cg * 8 + j];

        // gather-add-relu into Hs: wave covers 4 edges/pass x 4 waves = 16/pass
#pragma unroll
        for (int pass = 0; pass < 8; ++pass) {
            int row = pass * 16 + w * 4 + er;
            int i0 = i0s[row], i1 = i1s[row];
            bf16x8 p0 = *(const bf16x8*)(P0 + (size_t)i0 * HIDD + c * 128 + cg * 8);
            bf16x8 p1 = *(const bf16x8*)(P1 + (size_t)i1 * HIDD + c * 128 + cg * 8);
            ushort_t o[8];
#pragma unroll
            for (int j = 0; j < 8; ++j) {
                float v = bf2f((ushort_t)p0[j]) + bf2f((ushort_t)p1[j]) + bch[j];
                o[j] = f2bf(fmaxf(v, 0.f));
            }
            int slot = cg ^ (row & 7);
            *(int4*)&Hs[row * 128 + slot * 8] = *(int4*)o;
        }

        for (int k0h = 0; k0h < 128; k0h += 64) {
#pragma unroll
            for (int i = 0; i < 4; ++i) {
                int ch = w * 4 + i;
                int row = ch * 8 + srow;
                gload_lds16(W2t + (size_t)row * HIDD + c * 128 + k0h + sseg * 8,
                            Ws + ch * 512);
            }
            __syncthreads();   // covers Hs writes + Ws stage
#pragma unroll
            for (int ks = 0; ks < 2; ++ks) {
                bf16x8 af[4], bf[4];
#pragma unroll
                for (int mt = 0; mt < 4; ++mt) {
                    int row = wm * 64 + mt * 16 + lr;
                    int seg = (k0h >> 3) + ks * 4 + lg;
                    int slot = seg ^ (row & 7);
                    af[mt] = *(const bf16x8*)&Hs[row * 128 + slot * 8];
                }
#pragma unroll
                for (int nt = 0; nt < 4; ++nt) {
                    int row = wn * 64 + nt * 16 + lr;
                    int slot = (ks * 4 + lg) ^ (row & 7);
                    bf[nt] = *(const bf16x8*)&Ws[row * 64 + slot * 8];
                }
#pragma unroll
                for (int mt = 0; mt < 4; ++mt)
#pragma unroll
                    for (int nt = 0; nt < 4; ++nt)
                        acc2[mt][nt] = __builtin_amdgcn_mfma_f32_16x16x32_bf16(
                            af[mt], bf[nt], acc2[mt][nt], 0, 0, 0);
            }
            __syncthreads();
        }
    }

#pragma unroll
    for (int nt = 0; nt < 4; ++nt) {
        int col = wn * 64 + nt * 16 + lr;
        float bv = b2[col];
#pragma unroll
        for (int mt = 0; mt < 4; ++mt) {
#pragma unroll
            for (int r = 0; r < 4; ++r) {
                int row = m0 + wm * 64 + mt * 16 + lg * 4 + r;
                if (row >= M) continue;
                float v = fmaxf(acc2[mt][nt][r] + bv, 0.f);
                Cv[(size_t)row * 128 + col] = v;
            }
        }
    }
}

// ---------------------------------------------------------------------------
// embeddings = l2norm(h2 @ Wc3 + bc3); THREAD-per-row; h2 bf16.
// ---------------------------------------------------------------------------
__global__ __launch_bounds__(256) void emb_kernel(
    const ushort_t* __restrict__ h2, const float* __restrict__ W,
    const float* __restrict__ bias, float* __restrict__ out, int M)
{
    __shared__ float Wl[HIDD * EMBD];
    for (int i = threadIdx.x; i < HIDD * EMBD; i += 256) Wl[i] = W[i];
    __syncthreads();

    int m = blockIdx.x * 256 + threadIdx.x;
    if (m >= M) return;
    const ushort_t* row = h2 + (size_t)m * HIDD;

    float acc[EMBD] = {};
#pragma unroll 2
    for (int k0 = 0; k0 < HIDD; k0 += 8) {
        bf16x8 v = *(const bf16x8*)(row + k0);
        float f[8];
#pragma unroll
        for (int u = 0; u < 8; ++u) f[u] = bf2f((ushort_t)v[u]);
#pragma unroll
        for (int u = 0; u < 8; ++u) {
            const float* wr = &Wl[(k0 + u) * EMBD];
#pragma unroll
            for (int j = 0; j < EMBD; ++j) acc[j] += f[u] * wr[j];
        }
    }
    float vv[EMBD];
    float ss = 0.f;
#pragma unroll
    for (int j = 0; j < EMBD; ++j) { vv[j] = acc[j] + bias[j]; ss += vv[j] * vv[j]; }
    float inv = 1.f / fmaxf(sqrtf(ss), 1e-12f);
#pragma unroll
    for (int j = 0; j < EMBD; ++j) out[(size_t)m * EMBD + j] = vv[j] * inv;
}

// ---------------------------------------------------------------------------
__global__ void cluster_accum(const float* __restrict__ emb,
                              const int* __restrict__ clusters,
                              float* __restrict__ csums, float* __restrict__ ccnt)
{
    int n = blockIdx.x * 256 + threadIdx.x;
    if (n >= NN) return;
    int c = clusters[n];
    const float4* row = (const float4*)(emb + (size_t)n * EMBD);
    float4 r0 = row[0], r1 = row[1], r2 = row[2];
    float* dst = &csums[(size_t)c * EMBD];
    atomicAdd(&dst[0], r0.x);  atomicAdd(&dst[1], r0.y);
    atomicAdd(&dst[2], r0.z);  atomicAdd(&dst[3], r0.w);
    atomicAdd(&dst[4], r1.x);  atomicAdd(&dst[5], r1.y);
    atomicAdd(&dst[6], r1.z);  atomicAdd(&dst[7], r1.w);
    atomicAdd(&dst[8], r2.x);  atomicAdd(&dst[9], r2.y);
    atomicAdd(&dst[10], r2.z); atomicAdd(&dst[11], r2.w);
    atomicAdd(&ccnt[c], 1.f);
}

__global__ void means_kernel(const float* __restrict__ csums,
                             const float* __restrict__ ccnt,
                             float* __restrict__ means)
{
    int c = blockIdx.x * 256 + threadIdx.x;
    if (c >= NC) return;
    float cv = fmaxf(ccnt[c], 1.f);
    float v[EMBD];
    float ss = 0.f;
#pragma unroll
    for (int j = 0; j < EMBD; ++j) {
        v[j] = csums[(size_t)c * EMBD + j] / cv;
        ss += v[j] * v[j];
    }
    float inv = 1.f / fmaxf(sqrtf(ss), 1e-12f);
#pragma unroll
    for (int j = 0; j < EMBD; ++j) means[(size_t)c * EMBD + j] = v[j] * inv;
}

// ---------------------------------------------------------------------------
__device__ __forceinline__ void block_stats2(float x, float x2, float* s_sum, float* s_sumsq)
{
#pragma unroll
    for (int s = 32; s >= 1; s >>= 1) {
        x += __shfl_xor(x, s, 64);
        x2 += __shfl_xor(x2, s, 64);
    }
    __shared__ float w0[4], w1[4];
    int lane = threadIdx.x & 63, w = threadIdx.x >> 6;
    if (lane == 0) { w0[w] = x; w1[w] = x2; }
    __syncthreads();
    if (threadIdx.x == 0) {
        float a = 0.f, b = 0.f;
        for (int i = 0; i < 4; ++i) { a += w0[i]; b += w1[i]; }
        atomicAdd(s_sum, a);
        atomicAdd(s_sumsq, b);
    }
}

// ---------------------------------------------------------------------------
__global__ __launch_bounds__(256) void sg_lik_kernel(
    const float* __restrict__ means, const int* __restrict__ sg0,
    const int* __restrict__ sg1, float* __restrict__ sg_lik, float* __restrict__ stats)
{
    int base = (blockIdx.x * 256 + threadIdx.x) * 4;
    float xs = 0.f, xs2 = 0.f;
    if (base < NES) {
        int4 a4 = *(const int4*)(sg0 + base);
        int4 b4 = *(const int4*)(sg1 + base);
        int ai[4] = {a4.x, a4.y, a4.z, a4.w};
        int bi[4] = {b4.x, b4.y, b4.z, b4.w};
        float4 av[4][3], bv[4][3];
#pragma unroll
        for (int i = 0; i < 4; ++i) {
            const float4* ap = (const float4*)(means + (size_t)ai[i] * EMBD);
            const float4* bp = (const float4*)(means + (size_t)bi[i] * EMBD);
            av[i][0] = ap[0]; av[i][1] = ap[1]; av[i][2] = ap[2];
            bv[i][0] = bp[0]; bv[i][1] = bp[1]; bv[i][2] = bp[2];
        }
        float4 o;
        float* op = (float*)&o;
#pragma unroll
        for (int i = 0; i < 4; ++i) {
            float s = av[i][0].x * bv[i][0].x + av[i][0].y * bv[i][0].y
                    + av[i][0].z * bv[i][0].z + av[i][0].w * bv[i][0].w
                    + av[i][1].x * bv[i][1].x + av[i][1].y * bv[i][1].y
                    + av[i][1].z * bv[i][1].z + av[i][1].w * bv[i][1].w
                    + av[i][2].x * bv[i][2].x + av[i][2].y * bv[i][2].y
                    + av[i][2].z * bv[i][2].z + av[i][2].w * bv[i][2].w;
            op[i] = s;
            xs += s; xs2 += s * s;
        }
        *(float4*)(sg_lik + base) = o;
    }
    block_stats2(xs, xs2, &stats[0], &stats[1]);
}

__global__ __launch_bounds__(256) void sgw_kernel(
    const float* __restrict__ sg_lik, const float* __restrict__ stats,
    const float* __restrict__ gamma, const float* __restrict__ beta,
    float* __restrict__ out)
{
    int base = (blockIdx.x * 256 + threadIdx.x) * 4;
    if (base >= NES) return;
    float m = stats[0] / (float)NES;
    float var = stats[1] / (float)NES - m * m;
    float rs = rsqrtf(var + 1e-5f) * gamma[0];
    float4 v = *(const float4*)(sg_lik + base);
    float4 o;
    o.x = 1.f / (1.f + __expf(-((v.x - m) * rs + beta[0])));
    o.y = 1.f / (1.f + __expf(-((v.y - m) * rs + beta[0])));
    o.z = 1.f / (1.f + __expf(-((v.z - m) * rs + beta[0])));
    o.w = 1.f / (1.f + __expf(-((v.w - m) * rs + beta[0])));
    *(float4*)(out + base) = o;
}

// ---------------------------------------------------------------------------
__global__ __launch_bounds__(256) void bg_lik_kernel(
    const float* __restrict__ emb, const float* __restrict__ means,
    const int* __restrict__ bg_src, const int* __restrict__ bg_dst,
    float* __restrict__ bg_lik, float* __restrict__ stats, int* __restrict__ cnt)
{
    int base = (blockIdx.x * 256 + threadIdx.x) * 4;
    float xs = 0.f, xs2 = 0.f;
    if (base < NEB) {
        int4 s4 = *(const int4*)(bg_src + base);
        int4 d4 = *(const int4*)(bg_dst + base);
        int si[4] = {s4.x, s4.y, s4.z, s4.w};
        int di[4] = {d4.x, d4.y, d4.z, d4.w};
        float4 av[4][3], bv[4][3];
#pragma unroll
        for (int i = 0; i < 4; ++i) {
            const float4* ap = (const float4*)(emb + (size_t)si[i] * EMBD);
            const float4* bp = (const float4*)(means + (size_t)di[i] * EMBD);
            av[i][0] = ap[0]; av[i][1] = ap[1]; av[i][2] = ap[2];
            bv[i][0] = bp[0]; bv[i][1] = bp[1]; bv[i][2] = bp[2];
        }
#pragma unroll
        for (int i = 0; i < 4; ++i) atomicAdd(&cnt[di[i]], 1);
        float4 o;
        float* op = (float*)&o;
#pragma unroll
        for (int i = 0; i < 4; ++i) {
            float s = av[i][0].x * bv[i][0].x + av[i][0].y * bv[i][0].y
                    + av[i][0].z * bv[i][0].z + av[i][0].w * bv[i][0].w
                    + av[i][1].x * bv[i][1].x + av[i][1].y * bv[i][1].y
                    + av[i][1].z * bv[i][1].z + av[i][1].w * bv[i][1].w
                    + av[i][2].x * bv[i][2].x + av[i][2].y * bv[i][2].y
                    + av[i][2].z * bv[i][2].z + av[i][2].w * bv[i][2].w;
            op[i] = s;
            xs += s; xs2 += s * s;
        }
        *(float4*)(bg_lik + base) = o;
    }
    block_stats2(xs, xs2, &stats[2], &stats[3]);
}

__global__ __launch_bounds__(256) void bw_kernel(
    const float* __restrict__ bg_lik, const float* __restrict__ stats,
    const float* __restrict__ gamma, const float* __restrict__ beta,
    const int* __restrict__ bg_src, float* __restrict__ bw, float* __restrict__ denom)
{
    int base = (blockIdx.x * 256 + threadIdx.x) * 4;
    if (base >= NEB) return;
    float m = stats[2] / (float)NEB;
    float var = stats[3] / (float)NEB - m * m;
    float rs = rsqrtf(var + 1e-5f) * gamma[0];
    int4 s4 = *(const int4*)(bg_src + base);
    int si[4] = {s4.x, s4.y, s4.z, s4.w};
    float4 v = *(const float4*)(bg_lik + base);
    float vi[4] = {v.x, v.y, v.z, v.w};
    float4 o;
    float* op = (float*)&o;
#pragma unroll
    for (int i = 0; i < 4; ++i) {
        float w = __expf((vi[i] - m) * rs + beta[0]);
        op[i] = w;
        atomicAdd(&denom[si[i]], w);
    }
    *(float4*)(bw + base) = o;
}

__global__ __launch_bounds__(256) void bw_norm_kernel(
    float* __restrict__ bw, const float* __restrict__ denom,
    const int* __restrict__ bg_src, float* __restrict__ out)
{
    int base = (blockIdx.x * 256 + threadIdx.x) * 4;
    if (base >= NEB) return;
    int4 s4 = *(const int4*)(bg_src + base);
    int si[4] = {s4.x, s4.y, s4.z, s4.w};
    float dv[4];
#pragma unroll
    for (int i = 0; i < 4; ++i) dv[i] = denom[si[i]];
    float4 v = *(const float4*)(bw + base);
    float4 o;
    o.x = v.x / (1e-12f + dv[0]);
    o.y = v.y / (1e-12f + dv[1]);
    o.z = v.z / (1e-12f + dv[2]);
    o.w = v.w / (1e-12f + dv[3]);
    *(float4*)(bw + base) = o;
    *(float4*)(out + base) = o;
}

// ---------------------------------------------------------------------------
__global__ __launch_bounds__(1024) void scan_kernel(
    const int* __restrict__ cnt, int* __restrict__ offs, int C)
{
    __shared__ int wsum[16];
    __shared__ int carry_s, ctot_s;
    const int tid = threadIdx.x;
    const int lane = tid & 63, w = tid >> 6;
    if (tid == 0) carry_s = 0;
    __syncthreads();
    for (int base = 0; base < C; base += 1024) {
        int i = base + tid;
        int v = (i < C) ? cnt[i] : 0;
        int x = v;
#pragma unroll
        for (int s = 1; s < 64; s <<= 1) {
            int y = __shfl_up(x, s, 64);
            if (lane >= s) x += y;
        }
        if (lane == 63) wsum[w] = x;
        __syncthreads();
        if (tid == 0) {
            int s = 0;
            for (int k = 0; k < 16; ++k) { int t = wsum[k]; wsum[k] = s; s += t; }
            ctot_s = s;
        }
        __syncthreads();
        int excl = carry_s + wsum[w] + (x - v);
        if (i < C) offs[i] = excl;
        __syncthreads();
        if (tid == 0) carry_s += ctot_s;
        __syncthreads();
    }
    if (tid == 0) offs[C] = carry_s;
}

__global__ void scatter_kernel(const int* __restrict__ bg_dst,
                               const int* __restrict__ offs,
                               int* __restrict__ fill, int* __restrict__ eids)
{
    int base = (blockIdx.x * 256 + threadIdx.x) * 4;
    if (base >= NEB) return;
    int4 d4 = *(const int4*)(bg_dst + base);
    int di[4] = {d4.x, d4.y, d4.z, d4.w};
#pragma unroll
    for (int i = 0; i < 4; ++i) {
        int p = atomicAdd(&fill[di[i]], 1);
        eids[offs[di[i]] + p] = base + i;
    }
}

// ---------------------------------------------------------------------------
// supernodes: lane-packed gather (16 lanes x 16B = one 256B row per instr)
// ---------------------------------------------------------------------------
__global__ __launch_bounds__(256) void supernodes_kernel(
    const ushort_t* __restrict__ nmsg, const float* __restrict__ bw,
    const int* __restrict__ bg_src, const int* __restrict__ eids,
    const int* __restrict__ offs, float* __restrict__ sn)
{
    __shared__ float red[4][LATD];
    const int c = blockIdx.x;
    const int tid = threadIdx.x;
    const int wv = tid >> 6, lane = tid & 63;
    const int er = lane >> 4;
    const int cg = lane & 15;
    const int beg = offs[c], end = offs[c + 1];

    float acc[8] = {};
    for (int p = beg + wv * 4 + er; p < end; p += 16) {
        int e = eids[p];
        int s = bg_src[e];
        float w = bw[e];
        bf16x8 v = *(const bf16x8*)(nmsg + (size_t)s * LATD + cg * 8);
#pragma unroll
        for (int j = 0; j < 8; ++j) acc[j] += w * bf2f((ushort_t)v[j]);
    }
#pragma unroll
    for (int j = 0; j < 8; ++j) {
        acc[j] += __shfl_xor(acc[j], 16, 64);
        acc[j] += __shfl_xor(acc[j], 32, 64);
    }
    if (lane < 16) {
        *(float4*)&red[wv][cg * 8]     = (float4){acc[0], acc[1], acc[2], acc[3]};
        *(float4*)&red[wv][cg * 8 + 4] = (float4){acc[4], acc[5], acc[6], acc[7]};
    }
    __syncthreads();
    if (tid < LATD) {
        float s = red[0][tid] + red[1][tid] + red[2][tid] + red[3][tid];
        sn[(size_t)c * LATD + tid] = s;
    }
}

// ---------------------------------------------------------------------------
extern "C" void kernel_launch(void* const* d_in, const int* in_sizes, int n_in,
                              void* d_out, int out_size, void* d_ws, size_t ws_size,
                              hipStream_t stream)
{
    const float* emb_nodes = (const float*)d_in[0];
    const float* enc_nodes = (const float*)d_in[1];
    const float* Wc1 = (const float*)d_in[2];  const float* bc1 = (const float*)d_in[3];
    const float* Wc2 = (const float*)d_in[4];  const float* bc2 = (const float*)d_in[5];
    const float* Wc3 = (const float*)d_in[6];  const float* bc3 = (const float*)d_in[7];
    const float* Wn1 = (const float*)d_in[8];  const float* cn1 = (const float*)d_in[9];
    const float* Wn2 = (const float*)d_in[10]; const float* cn2 = (const float*)d_in[11];
    const float* We1 = (const float*)d_in[12]; const float* ce1 = (const float*)d_in[13];
    const float* We2 = (const float*)d_in[14]; const float* ce2 = (const float*)d_in[15];
    const float* sg_gamma = (const float*)d_in[16]; const float* sg_beta = (const float*)d_in[17];
    const float* bg_gamma = (const float*)d_in[18]; const float* bg_beta = (const float*)d_in[19];
    const int* clusters = (const int*)d_in[20];
    const int* sg0 = (const int*)d_in[21];
    const int* sg1 = sg0 + NES;
    const int* bg_src = (const int*)d_in[22];
    const int* bg_dst = (const int*)d_in[23];

    // output layout (flat, return order)
    float* out_emb = (float*)d_out;                       // NN*EMBD
    float* out_sn  = out_emb + (size_t)NN * EMBD;         // NC*LATD
    float* out_se  = out_sn + (size_t)NC * LATD;          // NES*LATD
    float* out_bw  = out_se + (size_t)NES * LATD;         // NEB
    float* out_sew = out_bw + (size_t)NEB;                // NES

    // ---------------- workspace layout (byte cursor, 64B-aligned) ----------
    uintptr_t cur = (uintptr_t)d_ws;
    uintptr_t wend = cur + ws_size;
    auto alloc = [&](size_t bytes) -> void* {
        cur = (cur + 63) & ~(uintptr_t)63;
        void* p = (void*)cur;
        cur += bytes;
        return p;
    };

    // zeroed region (contiguous): csums, ccnt, denom, stats, cnt, fill, zbias
    size_t zfloats = (size_t)NC * EMBD + NC + NN + 8 + NC + NC + HIDD;
    float* zbase = (float*)alloc(zfloats * 4);
    float* csums = zbase;
    float* ccnt  = csums + (size_t)NC * EMBD;
    float* denom = ccnt + NC;
    float* stats = denom + NN;
    int*   cnt   = (int*)(stats + 8);
    int*   fill  = cnt + NC;
    float* zbias = (float*)(fill + NC);         // HIDD zeros
    size_t zero_bytes = zfloats * 4;

    float* means  = (float*)alloc((size_t)NC * EMBD * 4);
    float* sg_lik = (float*)alloc((size_t)NES * 4);
    float* bg_lik = (float*)alloc((size_t)NEB * 4);
    float* bwv    = (float*)alloc((size_t)NEB * 4);
    int*   offs   = (int*)alloc((size_t)(NC + 1) * 4);
    int*   eids   = (int*)alloc((size_t)NEB * 4);

    ushort_t* xemb   = (ushort_t*)alloc((size_t)NN * LATD * 2);
    ushort_t* xenc   = (ushort_t*)alloc((size_t)NN * LATD * 2);
    ushort_t* nmsgb  = (ushort_t*)alloc((size_t)NN * LATD * 2);
    ushort_t* sn_bf  = (ushort_t*)alloc((size_t)NC * LATD * 2);
    ushort_t* P0b    = (ushort_t*)alloc((size_t)NC * HIDD * 2);
    ushort_t* P1b    = (ushort_t*)alloc((size_t)NC * HIDD * 2);
    ushort_t* Wc1t  = (ushort_t*)alloc((size_t)LATD * HIDD * 2);
    ushort_t* Wc2t  = (ushort_t*)alloc((size_t)HIDD * HIDD * 2);
    ushort_t* Wn1t  = (ushort_t*)alloc((size_t)LATD * HIDD * 2);
    ushort_t* Wn2t  = (ushort_t*)alloc((size_t)HIDD * LATD * 2);
    ushort_t* We1tA = (ushort_t*)alloc((size_t)HIDD * LATD * 2);  // [512][128]
    ushort_t* We1tB = (ushort_t*)alloc((size_t)HIDD * LATD * 2);  // [512][128]
    ushort_t* We2t  = (ushort_t*)alloc((size_t)HIDD * LATD * 2);  // [128][512]

    cur = (cur + 63) & ~(uintptr_t)63;
    size_t rem_bytes = (wend > cur) ? (size_t)(wend - cur) : 0;
    size_t chunk_sz = (rem_bytes / (2 * (size_t)HIDD * 2)) & ~(size_t)127;
    if (chunk_sz > 51200) chunk_sz = 51200;
    if (chunk_sz < 256) return;  // fail soft
    const int CH = (int)chunk_sz;
    ushort_t* bufA = (ushort_t*)cur;
    ushort_t* bufB = bufA + (size_t)CH * HIDD;

    hipMemsetAsync(zbase, 0, zero_bytes, stream);

    dim3 blk(256);

    // ---- prep: input/weight conversions ----
    conv_f2b_kernel<<<2048, blk, 0, stream>>>(emb_nodes, xemb, (long)NN * LATD);
    conv_f2b_kernel<<<2048, blk, 0, stream>>>(enc_nodes, xenc, (long)NN * LATD);
    transpose_conv_kernel<<<(LATD * HIDD + 255) / 256, blk, 0, stream>>>(Wc1, Wc1t, LATD, HIDD);
    transpose_conv_kernel<<<(HIDD * HIDD + 255) / 256, blk, 0, stream>>>(Wc2, Wc2t, HIDD, HIDD);
    transpose_conv_kernel<<<(LATD * HIDD + 255) / 256, blk, 0, stream>>>(Wn1, Wn1t, LATD, HIDD);
    transpose_conv_kernel<<<(HIDD * LATD + 255) / 256, blk, 0, stream>>>(Wn2, Wn2t, HIDD, LATD);
    transpose_conv_kernel<<<(LATD * HIDD + 255) / 256, blk, 0, stream>>>(We1, We1tA, LATD, HIDD);
    transpose_conv_kernel<<<(LATD * HIDD + 255) / 256, blk, 0, stream>>>(We1 + (size_t)LATD * HIDD, We1tB, LATD, HIDD);
    transpose_conv_kernel<<<(HIDD * LATD + 255) / 256, blk, 0, stream>>>(We2, We2t, HIDD, LATD);

    // ---- fused node chain, chunked: xemb->h1->h2->embeddings ----
    for (int m0 = 0; m0 < NN; m0 += CH) {
        int cm = (NN - m0 < CH) ? (NN - m0) : CH;
        gemm_mfma<ACT_TANH, true><<<dim3(HIDD / 128, (cm + 127) / 128), blk, 0, stream>>>(
            xemb + (size_t)m0 * LATD, Wc1t, bc1, bufA, cm, HIDD, LATD);
        gemm_mfma<ACT_TANH, true><<<dim3(HIDD / 128, (cm + 127) / 128), blk, 0, stream>>>(
            bufA, Wc2t, bc2, bufB, cm, HIDD, HIDD);
        emb_kernel<<<(cm + 255) / 256, blk, 0, stream>>>(
            bufB, Wc3, bc3, out_emb + (size_t)m0 * EMBD, cm);
    }

    // ---- cluster means ----
    cluster_accum<<<(NN + 255) / 256, blk, 0, stream>>>(out_emb, clusters, csums, ccnt);
    means_kernel<<<(NC + 255) / 256, blk, 0, stream>>>(csums, ccnt, means);

    // ---- super edge weights (4 edges/thread) ----
    sg_lik_kernel<<<(NES / 4 + 255) / 256, blk, 0, stream>>>(means, sg0, sg1, sg_lik, stats);
    sgw_kernel<<<(NES / 4 + 255) / 256, blk, 0, stream>>>(sg_lik, stats, sg_gamma, sg_beta, out_sew);

    // ---- bipartite edge weights (hist fused; 4 edges/thread) ----
    bg_lik_kernel<<<(NEB / 4 + 255) / 256, blk, 0, stream>>>(out_emb, means, bg_src, bg_dst, bg_lik, stats, cnt);
    bw_kernel<<<(NEB / 4 + 255) / 256, blk, 0, stream>>>(bg_lik, stats, bg_gamma, bg_beta, bg_src, bwv, denom);
    bw_norm_kernel<<<(NEB / 4 + 255) / 256, blk, 0, stream>>>(bwv, denom, bg_src, out_bw);

    // ---- counting sort of edges by destination cluster ----
    scan_kernel<<<1, 1024, 0, stream>>>(cnt, offs, NC);
    scatter_kernel<<<(NEB / 4 + 255) / 256, blk, 0, stream>>>(bg_dst, offs, fill, eids);

    // ---- node messages: FUSED relu(relu(xenc@Wn1)@Wn2) -> nmsgb (bf16) ----
    fused_mlp<true><<<(NN + 127) / 128, blk, 0, stream>>>(
        xenc, Wn1t, cn1, Wn2t, cn2, nmsgb, NN);

    // ---- supernodes (sorted edge lists, no atomics; lane-packed gather) ----
    supernodes_kernel<<<NC, blk, 0, stream>>>(nmsgb, bwv, bg_src, eids, offs, out_sn);
    conv_f2b_kernel<<<512, blk, 0, stream>>>(out_sn, sn_bf, (long)NC * LATD);

    // ---- premultiply: P0 = sn@We1_top, P1 = sn@We1_bot (no bias/act) ----
    gemm_mfma<ACT_NONE, true><<<dim3(HIDD / 128, (NC + 127) / 128), blk, 0, stream>>>(
        sn_bf, We1tA, zbias, P0b, NC, HIDD, LATD);
    gemm_mfma<ACT_NONE, true><<<dim3(HIDD / 128, (NC + 127) / 128), blk, 0, stream>>>(
        sn_bf, We1tB, zbias, P1b, NC, HIDD, LATD);

    // ---- superedges: FUSED relu(relu(P0[sg0]+P1[sg1]+ce1)@We2+ce2) ----
    fused_edge<<<(NES + 127) / 128, blk, 0, stream>>>(
        P0b, P1b, ce1, We2t, ce2, out_se, NES, sg0, sg1);
}